// Round 12
// baseline (4929.481 us; speedup 1.0000x reference)
//
#include <hip/hip_runtime.h>
#include <hip/hip_bf16.h>
#include <math.h>

#define NN 118
#define TT 2048
#define NF 64
#define DP 128
#define DN 256

typedef float v2f __attribute__((ext_vector_type(2)));
typedef _Float16 f16x4 __attribute__((ext_vector_type(4)));
typedef _Float16 f16x8 __attribute__((ext_vector_type(8)));
typedef float f32x4 __attribute__((ext_vector_type(4)));

__device__ __forceinline__ float leaky(float x) { return x > 0.f ? x : 0.01f * x; }

__device__ __forceinline__ float waveRedSum(float v) {
#pragma unroll
    for (int off = 32; off > 0; off >>= 1) v += __shfl_down(v, off, 64);
    return v;
}
__device__ __forceinline__ float waveRedMax(float v) {
#pragma unroll
    for (int off = 32; off > 0; off >>= 1) v = fmaxf(v, __shfl_down(v, off, 64));
    return v;
}

__device__ __forceinline__ float sigmoidf_(float x) { return 1.0f / (1.0f + __expf(-x)); }
__device__ __forceinline__ float tanhf_(float x) { return 1.0f - 2.0f / (__expf(2.0f * x) + 1.0f); }

// pack two f32 into f16x2 word with RNE rounding
__device__ __forceinline__ unsigned int pack_h2(float x, float y) {
    _Float16 a = (_Float16)x, b = (_Float16)y;
    unsigned short ua = __builtin_bit_cast(unsigned short, a);
    unsigned short ub = __builtin_bit_cast(unsigned short, b);
    return (unsigned int)ua | ((unsigned int)ub << 16);
}
// r-th f16 (r=0..3) of a uint2 as float
template <int R>
__device__ __forceinline__ float h2f_at(uint2 q) {
    unsigned int w = (R < 2) ? q.x : q.y;
    unsigned short us = (R & 1) ? (unsigned short)(w >> 16) : (unsigned short)w;
    return (float)__builtin_bit_cast(_Float16, us);
}

// ---------------- GEMM: out[M,512] = A[M,KK] @ W[512,KK]^T + (b1+b2) ---------------
// R14: MFMA (v_mfma_f32_16x16x16f16), 64x64 tile, f16 LDS with permuted k-slots
// (both operands share the permutation -> contraction is permutation-invariant).
template <int KK, typename TA>
__global__ __launch_bounds__(256) void xg_gemm(
    const TA* __restrict__ A, const float* __restrict__ W,
    const float* __restrict__ b1, const float* __restrict__ b2,
    _Float16* __restrict__ out, int rowStride, int rowOff, int lgTc) {
    const int KP = KK + 8;               // padded row length in f16
    int m0 = blockIdx.x * 64, n0 = blockIdx.y * 64;
    int tid = threadIdx.x;
    __shared__ __align__(16) _Float16 As[64 * KP];
    __shared__ __align__(16) _Float16 Bs[64 * KP];
    const int SL = KK / 4;               // 4-elem slots per row
    const int NL = 64 * SL / 256;
    int Tcm = (1 << lgTc) - 1;
#pragma unroll
    for (int r = 0; r < NL; r++) {
        int f = r * 256 + tid;
        int mm = f / SL, kv = f % SL;
        int m = m0 + mm;
        int grow = (m >> lgTc) * rowStride + (m & Tcm) + rowOff;
        int slot = 32 * (kv >> 3) + 8 * (kv & 3) + 4 * ((kv >> 2) & 1);
        uint2 av;
        if constexpr (sizeof(TA) == 4) {
            float4 v = *(const float4*)&A[(size_t)grow * KK + 4 * kv];
            av.x = pack_h2(v.x, v.y); av.y = pack_h2(v.z, v.w);
        } else {
            av = *(const uint2*)&A[(size_t)grow * KK + 4 * kv];
        }
        *(uint2*)&As[mm * KP + slot] = av;
        float4 wv = *(const float4*)&W[(size_t)(n0 + mm) * KK + 4 * kv];
        uint2 bv; bv.x = pack_h2(wv.x, wv.y); bv.y = pack_h2(wv.z, wv.w);
        *(uint2*)&Bs[mm * KP + slot] = bv;
    }
    __syncthreads();

    int lane = tid & 63, wave = tid >> 6;
    int wm = (wave >> 1) * 32, wn = (wave & 1) * 32;
    int l15 = lane & 15, gg = lane >> 4;
    f32x4 acc[2][2] = {};
#pragma unroll
    for (int t = 0; t < KK / 32; t++) {
        int ko = 32 * t + 8 * gg;
        f16x8 a0 = *(const f16x8*)&As[(wm + l15) * KP + ko];
        f16x8 a1 = *(const f16x8*)&As[(wm + 16 + l15) * KP + ko];
        f16x8 b0 = *(const f16x8*)&Bs[(wn + l15) * KP + ko];
        f16x8 b1 = *(const f16x8*)&Bs[(wn + 16 + l15) * KP + ko];
        f16x4 a0l = __builtin_shufflevector(a0, a0, 0, 1, 2, 3);
        f16x4 a0h = __builtin_shufflevector(a0, a0, 4, 5, 6, 7);
        f16x4 a1l = __builtin_shufflevector(a1, a1, 0, 1, 2, 3);
        f16x4 a1h = __builtin_shufflevector(a1, a1, 4, 5, 6, 7);
        f16x4 b0l = __builtin_shufflevector(b0, b0, 0, 1, 2, 3);
        f16x4 b0h = __builtin_shufflevector(b0, b0, 4, 5, 6, 7);
        f16x4 b1l = __builtin_shufflevector(b1, b1, 0, 1, 2, 3);
        f16x4 b1h = __builtin_shufflevector(b1, b1, 4, 5, 6, 7);
        acc[0][0] = __builtin_amdgcn_mfma_f32_16x16x16f16(a0l, b0l, acc[0][0], 0, 0, 0);
        acc[0][1] = __builtin_amdgcn_mfma_f32_16x16x16f16(a0l, b1l, acc[0][1], 0, 0, 0);
        acc[1][0] = __builtin_amdgcn_mfma_f32_16x16x16f16(a1l, b0l, acc[1][0], 0, 0, 0);
        acc[1][1] = __builtin_amdgcn_mfma_f32_16x16x16f16(a1l, b1l, acc[1][1], 0, 0, 0);
        acc[0][0] = __builtin_amdgcn_mfma_f32_16x16x16f16(a0h, b0h, acc[0][0], 0, 0, 0);
        acc[0][1] = __builtin_amdgcn_mfma_f32_16x16x16f16(a0h, b1h, acc[0][1], 0, 0, 0);
        acc[1][0] = __builtin_amdgcn_mfma_f32_16x16x16f16(a1h, b0h, acc[1][0], 0, 0, 0);
        acc[1][1] = __builtin_amdgcn_mfma_f32_16x16x16f16(a1h, b1h, acc[1][1], 0, 0, 0);
    }
#pragma unroll
    for (int i = 0; i < 2; i++)
#pragma unroll
        for (int j = 0; j < 2; j++) {
            int col = n0 + wn + j * 16 + l15;
            float bb = b1[col] + b2[col];
#pragma unroll
            for (int r = 0; r < 4; r++) {
                size_t row = (size_t)m0 + wm + i * 16 + gg * 4 + r;
                out[row * 512 + col] = (_Float16)(acc[i][j][r] + bb);
            }
        }
}

// ---------------- Batched-MFMA 2-layer LSTM recurrence -----------------------------
// R18: the per-cell structure was stuck at 1725 cyc/step (R16's barrier fix: null ->
// structural). Batch 16 sequences/block: per step G[512][16] = Whh @ H via
// v_mfma_f32_16x16x16f16 (M=512 gate-rows, N=16 seqs, K=128). Weights live in VGPRs
// as A-fragments (64 regs, loaded once); M-rows permuted so wave w / tile mt owns
// gate mt of units [16w,16w+16) -> each lane ends with ALL FOUR gates of its 4
// cells (D row-in-tile = 4*(l>>4)+r, col = l&15 = seq; layout verified by R14's
// passing gemm; both operands use canonical k = 16*kt + 4*(l>>4) + i). Cell update
// is lane-local (c in 4 regs); H (128x16 f16) double-buffered in LDS, rebuilt with
// one ds_write_b64/lane; x-contribution = 4 b64 gathers/lane, 2-deep prefetch
// (R13 full-register staging). Grid: (8 seq-groups, 2 layers); group 7 pads seqs
// 118..127 via clamped loads + predicated stores. One barrier/step (R16 LDS-only).
__global__ void
__attribute__((amdgpu_flat_work_group_size(512, 512), amdgpu_waves_per_eu(2, 2)))
lstm2_rec(
    const _Float16* __restrict__ xg0, const _Float16* __restrict__ xg1,
    const float* __restrict__ Whh0, const float* __restrict__ Whh1,
    float* __restrict__ h0s, float* __restrict__ c0s,
    float* __restrict__ h1s, float* __restrict__ c1s,
    _Float16* __restrict__ h1c, float* __restrict__ p_out,
    int phase, int nch, int Tc) {
    int layer = blockIdx.y;
    if (layer == 0 && phase >= nch) return;
    if (layer == 1 && phase == 0) return;
    const _Float16* __restrict__ xg = layer ? xg1 : xg0;
    const float* __restrict__ Whh = layer ? Whh1 : Whh0;
    float* hs = layer ? h1s : h0s;
    float* cs = layer ? c1s : c0s;
    int t_start = (layer ? (phase - 1) : phase) * Tc;

    int grp = blockIdx.x;
    int t = threadIdx.x;
    int w = t >> 6, l = t & 63;
    int s = l & 15, gg = l >> 4;
    int ubase = 16 * w + 4 * gg;         // first of this lane's 4 units
    int b = grp * 16 + s;
    int bc = (b < NN) ? b : (NN - 1);    // clamped for loads
    bool valid = b < NN;

    // H[buf][seq][unit + pad4]: pad makes ds_write banks spread across seqs
    __shared__ __align__(16) _Float16 Hb[2][16][132];

    // A-fragments: a[mt][kt]; lane supplies Whh[mt*128 + 16w + s][16kt + 4gg + i]
    f16x4 a[4][8];
#pragma unroll
    for (int mt = 0; mt < 4; mt++)
#pragma unroll
        for (int kt = 0; kt < 8; kt++) {
            float4 v = *(const float4*)&Whh[(size_t)(mt * 128 + 16 * w + s) * 128 + 16 * kt + 4 * gg];
            f16x4 av = {(_Float16)v.x, (_Float16)v.y, (_Float16)v.z, (_Float16)v.w};
            a[mt][kt] = av;
        }

    // persistent cell state (4 cells: units ubase..ubase+3, seq s)
    float c0_, c1_, c2_, c3_;
    {
        float4 tmp = *(const float4*)&cs[(size_t)bc * 128 + ubase];
        c0_ = tmp.x; c1_ = tmp.y; c2_ = tmp.z; c3_ = tmp.w;
    }
    // H init from hs
    {
        float4 hv = *(const float4*)&hs[(size_t)bc * 128 + ubase];
        uint2 hp; hp.x = pack_h2(hv.x, hv.y); hp.y = pack_h2(hv.z, hv.w);
        *(uint2*)&Hb[0][s][ubase] = hp;
    }
    const _Float16* xgb = xg + (size_t)bc * Tc * 512;
    // 2-deep x prefetch: 4 b64 per depth (one per gate), full-register staging
    uint2 xq0[4], xq1[4];
#pragma unroll
    for (int mt = 0; mt < 4; mt++) {
        xq0[mt] = *(const uint2*)&xgb[mt * 128 + ubase];
        xq1[mt] = *(const uint2*)&xgb[512 + mt * 128 + ubase];
    }
    __syncthreads();

    int cur = 0;
    float hl0 = 0.f, hl1 = 0.f, hl2 = 0.f, hl3 = 0.f;
#pragma unroll 1
    for (int tl = 0; tl < Tc; tl++) {
        uint2 xq2[4] = {};
        if (tl + 2 < Tc) {
#pragma unroll
            for (int mt = 0; mt < 4; mt++)
                xq2[mt] = *(const uint2*)&xgb[(size_t)(tl + 2) * 512 + mt * 128 + ubase];
        }
        f32x4 acc[4] = {};
#pragma unroll
        for (int kt = 0; kt < 8; kt++) {
            f16x4 bf = *(const f16x4*)&Hb[cur][s][16 * kt + 4 * gg];
            acc[0] = __builtin_amdgcn_mfma_f32_16x16x16f16(a[0][kt], bf, acc[0], 0, 0, 0);
            acc[1] = __builtin_amdgcn_mfma_f32_16x16x16f16(a[1][kt], bf, acc[1], 0, 0, 0);
            acc[2] = __builtin_amdgcn_mfma_f32_16x16x16f16(a[2][kt], bf, acc[2], 0, 0, 0);
            acc[3] = __builtin_amdgcn_mfma_f32_16x16x16f16(a[3][kt], bf, acc[3], 0, 0, 0);
        }
        // 4 lane-local cell updates (gate mt: 0=i 1=f 2=g 3=o)
#define CELL(R, CREG, HREG) { \
            float pi = acc[0][R] + h2f_at<R>(xq0[0]); \
            float pf = acc[1][R] + h2f_at<R>(xq0[1]); \
            float pg = acc[2][R] + h2f_at<R>(xq0[2]); \
            float po = acc[3][R] + h2f_at<R>(xq0[3]); \
            float i_ = sigmoidf_(pi), f_ = sigmoidf_(pf), o_ = sigmoidf_(po); \
            float g_ = tanhf_(pg); \
            CREG = f_ * CREG + i_ * g_; \
            HREG = o_ * tanhf_(CREG); }
        CELL(0, c0_, hl0)
        CELL(1, c1_, hl1)
        CELL(2, c2_, hl2)
        CELL(3, c3_, hl3)
#undef CELL
        uint2 hp; hp.x = pack_h2(hl0, hl1); hp.y = pack_h2(hl2, hl3);
        *(uint2*)&Hb[cur ^ 1][s][ubase] = hp;
        if (layer == 0) {
            if (valid) *(uint2*)&h1c[((size_t)b * Tc + tl) * 128 + ubase] = hp;
        } else if (t_start + tl == TT - 1) {
            if (valid) {
                float4 pv = {leaky(hl0), leaky(hl1), leaky(hl2), leaky(hl3)};
                *(float4*)&p_out[(size_t)b * 128 + ubase] = pv;
            }
        }
#pragma unroll
        for (int mt = 0; mt < 4; mt++) { xq0[mt] = xq1[mt]; xq1[mt] = xq2[mt]; }
        // LDS-only barrier (x prefetch + h1c stores stay in flight)
        asm volatile("s_waitcnt lgkmcnt(0)" ::: "memory");
        __builtin_amdgcn_s_barrier();
        __builtin_amdgcn_sched_barrier(0);
        cur ^= 1;
    }
    if (valid) {
        float4 cv = {c0_, c1_, c2_, c3_};
        *(float4*)&cs[(size_t)b * 128 + ubase] = cv;
        float4 hv = {hl0, hl1, hl2, hl3};
        *(float4*)&hs[(size_t)b * 128 + ubase] = hv;
    }
}

// ---------------- Head part 1: per-row i, everything up to n + precomputes ---------
__global__ __launch_bounds__(256) void head1_kernel(
    const float* __restrict__ x_message, const float* __restrict__ pseudo,
    const float* __restrict__ p_out,
    const float* __restrict__ Wum, const float* __restrict__ Wvm,
    const float* __restrict__ Wup, const float* __restrict__ Wvp,
    const float* __restrict__ Wpe, const float* __restrict__ bpe,
    const float* __restrict__ Whyb, const float* __restrict__ bhyb,
    const float* __restrict__ Wact, const float* __restrict__ bact,
    const float* __restrict__ Winact, const float* __restrict__ binact,
    const float* __restrict__ Wphin, const float* __restrict__ Won,
    const float* __restrict__ Weo,
    float* __restrict__ st_out, float* __restrict__ n_out, float* __restrict__ wnn_out,
    float* __restrict__ R_out, float* __restrict__ S_out,
    float* __restrict__ P_out, float* __restrict__ Q_out,
    float* __restrict__ A_out, float* __restrict__ B_out,
    float* __restrict__ d_out) {
    int i = blockIdx.x, tid = threadIdx.x;
    __shared__ float mc[769];
    __shared__ float pcp[128];
    __shared__ float um[128], vm[128], up[128], vp[128];
    __shared__ float hyb[256], nsh[256];
    __shared__ float red[4];
    __shared__ float sred[2][2];
    __shared__ float st_sh, hp0_sh, hp1_sh, wpol_sh, norm_sh;

    float s = 0.f;
    for (int q = tid; q < 768; q += 256) s += x_message[i * 768 + q];
    s = waveRedSum(s);
    if ((tid & 63) == 0) red[tid >> 6] = s;
    __syncthreads();
    if (tid == 0) {
        float tot = red[0] + red[1] + red[2] + red[3];
        float st = (tot == 0.f) ? 1.f : 0.f;
        st_sh = st; st_out[i] = st;
    }
    __syncthreads();
    float st = st_sh;
    for (int q = tid; q < 768; q += 256)
        mc[q] = (st == 1.f) ? pseudo[q] : x_message[i * 768 + q];
    if (tid == 0) mc[768] = st;
    if (tid < 128) pcp[tid] = p_out[i * 128 + tid];
    __syncthreads();

    if (tid < 128) {
        int d = tid;
        float a0 = 0.f;
        for (int q = 0; q < 769; q++) a0 += mc[q] * Wum[q * 128 + d];
        um[d] = leaky(a0);
        float a1 = 0.f;
        for (int q = 0; q < 128; q++) a1 += pcp[q] * Wup[q * 128 + d];
        a1 += st * Wup[128 * 128 + d];
        up[d] = leaky(a1);
    } else {
        int d = tid - 128;
        float a0 = 0.f;
        for (int q = 0; q < 769; q++) a0 += mc[q] * Wvm[q * 128 + d];
        vm[d] = leaky(a0);
        float a1 = 0.f;
        for (int q = 0; q < 128; q++) a1 += pcp[q] * Wvp[q * 128 + d];
        a1 += st * Wvp[128 * 128 + d];
        vp[d] = leaky(a1);
    }
    __syncthreads();

    float t0 = 0.f, t1 = 0.f;
    if (tid < 128) {
        int d = tid;
        float um_d = um[d], vp_d = vp[d], uv = um_d * vp_d;
        t0 = um_d * Wpe[d] + uv * Wpe[128 + d] + vp_d * Wpe[256 + d];
        t1 = um_d * Wpe[384 + d] + uv * Wpe[384 + 128 + d] + vp_d * Wpe[384 + 256 + d];
    }
    t0 = waveRedSum(t0); t1 = waveRedSum(t1);
    if (tid < 128 && (tid & 63) == 0) { sred[0][tid >> 6] = t0; sred[1][tid >> 6] = t1; }
    __syncthreads();
    if (tid == 0) {
        float z0 = sred[0][0] + sred[0][1] + bpe[0];
        float z1 = sred[1][0] + sred[1][1] + bpe[1];
        float mx = fmaxf(z0, z1);
        float e0 = __expf(z0 - mx), e1 = __expf(z1 - mx);
        float inv = 1.f / (e0 + e1);
        float h0 = e0 * inv, h1 = e1 * inv;
        d_out[236 + i * 2 + 0] = h0; d_out[236 + i * 2 + 1] = h1;
        hp0_sh = h0; hp1_sh = h1;
        float sgn = (z1 > z0) ? 1.f : ((z1 < z0) ? -1.f : 0.f);
        wpol_sh = (st == 0.f) ? sgn : 0.f;
    }
    __syncthreads();

    {
        float acc = bhyb[tid];
        const float* Wr = Whyb + tid * 384;
        for (int q = 0; q < 128; q++) {
            float upq = up[q], vmq = vm[q];
            acc += upq * Wr[q] + (upq + vmq) * Wr[128 + q] + vmq * Wr[256 + q];
        }
        hyb[tid] = leaky(acc);
    }
    __syncthreads();

    {
        float hp0 = hp0_sh, hp1 = hp1_sh;
        float aa = bact[tid];
        float ai = binact[tid];
        const float* Wr = Wact + tid * 258;
        const float* Wr2 = Winact + tid * 256;
        for (int q = 0; q < 256; q++) { float h = hyb[q]; aa += h * Wr[q]; ai += h * Wr2[q]; }
        aa += hp0 * Wr[256] + hp1 * Wr[257];
        float nv = leaky(aa * (1.f - st) + ai * st);
        nsh[tid] = nv; n_out[i * 256 + tid] = nv;
    }
    __syncthreads();

    float nv = nsh[tid];
    float ssum = waveRedSum(nv * nv);
    if ((tid & 63) == 0) red[tid >> 6] = ssum;
    __syncthreads();
    if (tid == 0) norm_sh = fmaxf(sqrtf(red[0] + red[1] + red[2] + red[3]), 1e-8f);
    __syncthreads();
    wnn_out[i * 256 + tid] = wpol_sh * nv / norm_sh;

    if (tid < 192) {
        float r = 0.f, sc = 0.f;
        for (int q = 0; q < 256; q++) {
            float nq = nsh[q];
            r += nq * Wphin[q * 192 + tid];
            sc += nq * Wphin[(256 + q) * 192 + tid];
        }
        R_out[i * 192 + tid] = r; S_out[i * 192 + tid] = sc;
    }
    {
        float pa = 0.f, qa = 0.f, aa = 0.f, ba = 0.f;
        for (int q = 0; q < 256; q++) {
            float nq = nsh[q];
            pa += nq * Won[q * 256 + tid];
            qa += nq * Won[(256 + q) * 256 + tid];
            aa += nq * Weo[(256 + q) * 256 + tid];
            ba += nq * Weo[(512 + q) * 256 + tid];
        }
        P_out[i * 256 + tid] = pa; Q_out[i * 256 + tid] = qa;
        A_out[i * 256 + tid] = aa; B_out[i * 256 + tid] = ba;
    }
}

// ---------------- l_ort via two-stage Gram ----------------------------------------
__global__ __launch_bounds__(256) void gram_kernel(
    const float* __restrict__ Wum, const float* __restrict__ Wvm,
    const float* __restrict__ Wup, const float* __restrict__ Wvp,
    float* __restrict__ G) {
    int which = blockIdx.y;
    const float* __restrict__ M = (which == 0) ? Wum : (which == 1) ? Wvm
                                 : (which == 2) ? Wup : Wvp;
    int R = (which < 2) ? 769 : 129;
    int tile = blockIdx.x;               // 16 tiles of 32x32 over the 128x128 output
    int ti = (tile >> 2) * 32, tj = (tile & 3) * 32;
    int t = threadIdx.x;
    __shared__ __align__(16) float Ls[64][32];
    __shared__ __align__(16) float Rs[64][32];
    int jj = t & 31, ib = (t >> 5) * 4;
    float acc0 = 0.f, acc1 = 0.f, acc2 = 0.f, acc3 = 0.f;
    for (int m0 = 0; m0 < R; m0 += 64) {
#pragma unroll
        for (int hh = 0; hh < 2; hh++) {
            int f = hh * 256 + t;        // 512 float4-slots = 64 rows x 8 segs
            int row = f >> 3, cseg = (f & 7) * 4;
            float4 lv = {0.f, 0.f, 0.f, 0.f}, rv = {0.f, 0.f, 0.f, 0.f};
            if (m0 + row < R) {
                lv = *(const float4*)&M[(size_t)(m0 + row) * 128 + ti + cseg];
                rv = *(const float4*)&M[(size_t)(m0 + row) * 128 + tj + cseg];
            }
            *(float4*)&Ls[row][cseg] = lv;
            *(float4*)&Rs[row][cseg] = rv;
        }
        __syncthreads();
#pragma unroll 4
        for (int m = 0; m < 64; m++) {
            float4 lv = *(const float4*)&Ls[m][ib];   // broadcast within 32-group
            float r = Rs[m][jj];                      // lane-distinct, conflict-free
            acc0 += lv.x * r; acc1 += lv.y * r; acc2 += lv.z * r; acc3 += lv.w * r;
        }
        __syncthreads();
    }
    float* Go = G + ((size_t)which << 14);
    Go[(size_t)(ti + ib + 0) * 128 + tj + jj] = acc0;
    Go[(size_t)(ti + ib + 1) * 128 + tj + jj] = acc1;
    Go[(size_t)(ti + ib + 2) * 128 + tj + jj] = acc2;
    Go[(size_t)(ti + ib + 3) * 128 + tj + jj] = acc3;
}

__global__ __launch_bounds__(256) void lort_red_kernel(
    const float* __restrict__ G, float* __restrict__ lort) {
    int which = blockIdx.x;              // 0: (Wum,Wvm)  1: (Wup,Wvp)
    const float* g1 = G + ((size_t)(2 * which) << 14);
    const float* g2 = g1 + (1 << 14);
    int t = threadIdx.x;
    __shared__ float red[4];
    float s = 0.f;
    for (int e = t; e < (1 << 14); e += 256) s += g1[e] * g2[e];
    s = waveRedSum(s);
    if ((t & 63) == 0) red[t >> 6] = s;
    __syncthreads();
    if (t == 0) lort[which] = red[0] + red[1] + red[2] + red[3];
}

// ---------------- phi(i,j) = leaky(R[j]+S[i]) . aphi  (stored column-major) --------
__global__ __launch_bounds__(128) void phi_kernel(
    const float* __restrict__ R, const float* __restrict__ S,
    const float* __restrict__ aphi, float* __restrict__ phi_cm) {
    int j = blockIdx.x, tid = threadIdx.x;
    __shared__ float rj[192], ap[192];
    for (int q = tid; q < 192; q += 128) { rj[q] = R[j * 192 + q]; ap[q] = aphi[q]; }
    __syncthreads();
    if (tid < NN) {
        const float* Si = S + tid * 192;
        float acc = 0.f;
        for (int d = 0; d < 192; d++) acc += leaky(rj[d] + Si[d]) * ap[d];
        phi_cm[j * NN + tid] = acc;
    }
}

// ---------------- double group-softmax over rows, per column ----------------------
__global__ __launch_bounds__(128) void alpha_kernel(
    const float* __restrict__ phi_cm, const float* __restrict__ stv,
    float* __restrict__ w0_cm, float* __restrict__ w1_cm) {
    int j = blockIdx.x, tid = threadIdx.x;
    __shared__ float sm[2][2], ssum[2][2];
    bool act = tid < NN;
    float sti = act ? stv[tid] : -1.f;
    float v = act ? phi_cm[j * NN + tid] : 0.f;
    float m0 = (sti == 0.f) ? v : -3.0e38f;
    float m1 = (sti == 1.f) ? v : -3.0e38f;
    float M0 = waveRedMax(m0), M1 = waveRedMax(m1);
    if ((tid & 63) == 0) { sm[tid >> 6][0] = M0; sm[tid >> 6][1] = M1; }
    __syncthreads();
    M0 = fmaxf(sm[0][0], sm[1][0]); M1 = fmaxf(sm[0][1], sm[1][1]);
    float e = 0.f;
    if (act) e = __expf(v - ((sti == 0.f) ? M0 : M1));
    float e0 = (sti == 0.f) ? e : 0.f, e1 = (sti == 1.f) ? e : 0.f;
    float S0 = waveRedSum(e0), S1 = waveRedSum(e1);
    if ((tid & 63) == 0) { ssum[tid >> 6][0] = S0; ssum[tid >> 6][1] = S1; }
    __syncthreads();
    S0 = ssum[0][0] + ssum[1][0]; S1 = ssum[0][1] + ssum[1][1];
    if (act) {
        float alpha = e / ((sti == 0.f) ? S0 : S1);
        w0_cm[j * NN + tid] = sti * alpha;
        w1_cm[j * NN + tid] = (1.f - sti) * alpha;
    }
}

// ---------------- per-row weighted sums over j ------------------------------------
__global__ __launch_bounds__(256) void qsum_kernel(
    const float* __restrict__ P, const float* __restrict__ Q, const float* __restrict__ Ab,
    const float* __restrict__ w0_cm, const float* __restrict__ w1_cm,
    float* __restrict__ qs0, float* __restrict__ qs1,
    float* __restrict__ as0, float* __restrict__ as1,
    float* __restrict__ ws0, float* __restrict__ ws1) {
    int i = blockIdx.x, d = threadIdx.x;
    float Qd = Q[i * 256 + d];
    float q0 = 0.f, q1 = 0.f, a0 = 0.f, a1 = 0.f, s0 = 0.f, s1 = 0.f;
    for (int jj = 0; jj < NN; jj++) {
        float w0 = w0_cm[jj * NN + i], w1 = w1_cm[jj * NN + i];
        float pq = leaky(P[jj * 256 + d] + Qd);
        float av = Ab[jj * 256 + d];
        q0 += w0 * pq; q1 += w1 * pq;
        a0 += w0 * av; a1 += w1 * av;
        s0 += w0; s1 += w1;
    }
    qs0[i * 256 + d] = q0; qs1[i * 256 + d] = q1;
    as0[i * 256 + d] = a0; as1[i * 256 + d] = a1;
    if (d == 0) { ws0[i] = s0; ws1[i] = s1; }
}

// ---------------- hm0/hm1, output head, y_hat -------------------------------------
__global__ __launch_bounds__(256) void hm_out_kernel(
    const float* __restrict__ qs0, const float* __restrict__ qs1,
    const float* __restrict__ as0, const float* __restrict__ as1,
    const float* __restrict__ ws0, const float* __restrict__ ws1,
    const float* __restrict__ Bb, const float* __restrict__ nbuf,
    const float* __restrict__ Weo, const float* __restrict__ Wi,
    const float* __restrict__ bi, float* __restrict__ d_out) {
    int i = blockIdx.x, d = threadIdx.x;
    __shared__ float q0sh[256], q1sh[256];
    __shared__ float r0[4], r1[4];
    q0sh[d] = qs0[i * 256 + d]; q1sh[d] = qs1[i * 256 + d];
    __syncthreads();
    float Bd = Bb[i * 256 + d];
    float h0 = as0[i * 256 + d] + ws0[i] * Bd;
    float h1 = as1[i * 256 + d] + ws1[i] * Bd;
    for (int k = 0; k < 256; k++) {
        float w = Weo[k * 256 + d];
        h0 += q0sh[k] * w; h1 += q1sh[k] * w;
    }
    h0 = leaky(h0); h1 = leaky(h1);
    float nd = nbuf[i * 256 + d];
    const float* Wii = Wi + (size_t)i * 1536;
    float l0 = nd * Wii[d * 2] + h0 * Wii[(256 + d) * 2] + h1 * Wii[(512 + d) * 2];
    float l1 = nd * Wii[d * 2 + 1] + h0 * Wii[(256 + d) * 2 + 1] + h1 * Wii[(512 + d) * 2 + 1];
    l0 = waveRedSum(l0); l1 = waveRedSum(l1);
    if ((d & 63) == 0) { r0[d >> 6] = l0; r1[d >> 6] = l1; }
    __syncthreads();
    if (d == 0) {
        float z0 = r0[0] + r0[1] + r0[2] + r0[3] + bi[i * 2 + 0];
        float z1 = r1[0] + r1[1] + r1[2] + r1[3] + bi[i * 2 + 1];
        float mx = fmaxf(z0, z1);
        float e0 = __expf(z0 - mx), e1 = __expf(z1 - mx);
        float inv = 1.f / (e0 + e1);
        d_out[i * 2 + 0] = e0 * inv;
        d_out[i * 2 + 1] = e1 * inv;
    }
}

// ---------------- l_pol + l_ort finalize ------------------------------------------
__global__ __launch_bounds__(256) void pol_kernel(
    const float* __restrict__ wnn, const float* __restrict__ lort,
    float* __restrict__ d_out) {
    int d = threadIdx.x;
    __shared__ float red[4];
    float s = 0.f;
    for (int i = 0; i < NN; i++) s += wnn[i * 256 + d];
    float p = waveRedSum(s * s);
    if ((d & 63) == 0) red[d >> 6] = p;
    __syncthreads();
    if (d == 0) {
        d_out[473] = red[0] + red[1] + red[2] + red[3];
        d_out[472] = sqrtf(lort[0]) + sqrtf(lort[1]);
    }
}

extern "C" void kernel_launch(void* const* d_in, const int* in_sizes, int n_in,
                              void* d_out_v, int out_size, void* d_ws, size_t ws_size,
                              hipStream_t stream) {
    (void)in_sizes; (void)n_in; (void)out_size;
    const float* x        = (const float*)d_in[0];
    const float* x_msg    = (const float*)d_in[1];
    const float* pseudo   = (const float*)d_in[2];
    const float* Wih0     = (const float*)d_in[3];
    const float* Whh0     = (const float*)d_in[4];
    const float* bih0     = (const float*)d_in[5];
    const float* bhh0     = (const float*)d_in[6];
    const float* Wih1     = (const float*)d_in[7];
    const float* Whh1     = (const float*)d_in[8];
    const float* bih1     = (const float*)d_in[9];
    const float* bhh1     = (const float*)d_in[10];
    const float* Wum      = (const float*)d_in[11];
    const float* Wvm      = (const float*)d_in[12];
    const float* Wup      = (const float*)d_in[13];
    const float* Wvp      = (const float*)d_in[14];
    const float* Wpe      = (const float*)d_in[15];
    const float* bpe      = (const float*)d_in[16];
    const float* Whyb     = (const float*)d_in[17];
    const float* bhyb     = (const float*)d_in[18];
    const float* Wact     = (const float*)d_in[19];
    const float* bact     = (const float*)d_in[20];
    const float* Winact   = (const float*)d_in[21];
    const float* binact   = (const float*)d_in[22];
    const float* Wphin    = (const float*)d_in[23];
    const float* aphi     = (const float*)d_in[24];
    const float* Won      = (const float*)d_in[25];
    const float* Weo      = (const float*)d_in[26];
    const float* Wi       = (const float*)d_in[27];
    const float* bi       = (const float*)d_in[28];
    float* out = (float*)d_out_v;

    char* wsb = (char*)d_ws;
    size_t off = 0;
    auto alloc = [&](size_t nfloats) {
        float* p = (float*)(wsb + off);
        off += ((nfloats * 4 + 255) / 256) * 256;
        return p;
    };
    auto allocB = [&](size_t nbytes) {
        char* p = wsb + off;
        off += ((nbytes + 255) / 256) * 256;
        return p;
    };
    float* h0s   = alloc(NN * 128);
    float* c0s   = alloc(NN * 128);
    float* h1s   = alloc(NN * 128);
    float* c1s   = alloc(NN * 128);
    float* lort  = alloc(2);
    float* stb   = alloc(NN);
    float* p_out = alloc(NN * 128);
    float* nbuf  = alloc(NN * 256);
    float* wnn   = alloc(NN * 256);
    float* Rb    = alloc(NN * 192);
    float* Sb    = alloc(NN * 192);
    float* Pb    = alloc(NN * 256);
    float* Qb    = alloc(NN * 256);
    float* Ab    = alloc(NN * 256);
    float* Bb    = alloc(NN * 256);
    float* qs0   = alloc(NN * 256);
    float* qs1   = alloc(NN * 256);
    float* as0   = alloc(NN * 256);
    float* as1   = alloc(NN * 256);
    float* ws0   = alloc(NN);
    float* ws1   = alloc(NN);
    float* phicm = alloc(NN * NN);
    float* w0cm  = alloc(NN * NN);
    float* w1cm  = alloc(NN * NN);
    float* gramB = alloc(4 * 128 * 128);

    size_t remain = (ws_size > off) ? (ws_size - off) : 0;
    // Tc capped at 256 — lstm total = (TT+Tc)*step_time, so bigger chunks only
    // enlarge the pipeline bubble; smaller ones multiply weight-reload fetch.
    int Tc = 256;
    // need xg0 + xg1 (f16, NN*Tc*512*2 B each) + h1c (f16, NN*Tc*128*2 B)
    while (Tc > 64 && (size_t)NN * Tc * (1024 + 1024 + 256) > remain) Tc >>= 1;
    _Float16* xg0 = (_Float16*)allocB((size_t)NN * Tc * 512 * 2);
    _Float16* xg1 = (_Float16*)allocB((size_t)NN * Tc * 512 * 2);
    _Float16* h1c = (_Float16*)allocB((size_t)NN * Tc * 128 * 2);
    int lgTc = __builtin_ctz(Tc);

    hipMemsetAsync(h0s, 0, (size_t)4 * NN * 128 * sizeof(float), stream); // h0s..c1s contiguous

    int nch = TT / Tc;
    dim3 gg((NN * Tc) / 64, 8);
    // prologue: xg0 for chunk 0
    xg_gemm<64, float><<<gg, 256, 0, stream>>>(x, Wih0, bih0, bhh0, xg0, TT, 0, lgTc);
    for (int p = 0; p <= nch; p++) {
        lstm2_rec<<<dim3(8, 2), 512, 0, stream>>>(xg0, xg1, Whh0, Whh1,
                                                  h0s, c0s, h1s, c1s,
                                                  h1c, p_out, p, nch, Tc);
        if (p < nch)
            xg_gemm<128, _Float16><<<gg, 256, 0, stream>>>(h1c, Wih1, bih1, bhh1, xg1, Tc, 0, lgTc);
        if (p + 1 < nch)
            xg_gemm<64, float><<<gg, 256, 0, stream>>>(x, Wih0, bih0, bhh0, xg0, TT, (p + 1) * Tc, lgTc);
    }
    head1_kernel<<<NN, 256, 0, stream>>>(x_msg, pseudo, p_out, Wum, Wvm, Wup, Wvp,
                                         Wpe, bpe, Whyb, bhyb, Wact, bact, Winact, binact,
                                         Wphin, Won, Weo,
                                         stb, nbuf, wnn, Rb, Sb, Pb, Qb, Ab, Bb, out);
    gram_kernel<<<dim3(16, 4), 256, 0, stream>>>(Wum, Wvm, Wup, Wvp, gramB);
    lort_red_kernel<<<2, 256, 0, stream>>>(gramB, lort);
    phi_kernel<<<NN, 128, 0, stream>>>(Rb, Sb, aphi, phicm);
    alpha_kernel<<<NN, 128, 0, stream>>>(phicm, stb, w0cm, w1cm);
    qsum_kernel<<<NN, 256, 0, stream>>>(Pb, Qb, Ab, w0cm, w1cm, qs0, qs1, as0, as1, ws0, ws1);
    hm_out_kernel<<<NN, 256, 0, stream>>>(qs0, qs1, as0, as1, ws0, ws1, Bb, nbuf, Weo, Wi, bi, out);
    pol_kernel<<<1, 256, 0, stream>>>(wnn, lort, out);
}

// Round 13
// 2737.607 us; speedup vs baseline: 1.8007x; 1.8007x over previous
//
#include <hip/hip_runtime.h>
#include <hip/hip_bf16.h>
#include <math.h>

#define NN 118
#define TT 2048
#define NF 64
#define DP 128
#define DN 256

typedef float v2f __attribute__((ext_vector_type(2)));
typedef _Float16 f16x4 __attribute__((ext_vector_type(4)));
typedef _Float16 f16x8 __attribute__((ext_vector_type(8)));
typedef float f32x4 __attribute__((ext_vector_type(4)));

__device__ __forceinline__ float leaky(float x) { return x > 0.f ? x : 0.01f * x; }

__device__ __forceinline__ float waveRedSum(float v) {
#pragma unroll
    for (int off = 32; off > 0; off >>= 1) v += __shfl_down(v, off, 64);
    return v;
}
__device__ __forceinline__ float waveRedMax(float v) {
#pragma unroll
    for (int off = 32; off > 0; off >>= 1) v = fmaxf(v, __shfl_down(v, off, 64));
    return v;
}

__device__ __forceinline__ float sigmoidf_(float x) { return 1.0f / (1.0f + __expf(-x)); }
__device__ __forceinline__ float tanhf_(float x) { return 1.0f - 2.0f / (__expf(2.0f * x) + 1.0f); }

// sum across the 4 lanes of a quad via DPP quad_perm (VALU pipe, no LDS traffic)
__device__ __forceinline__ float quad_sum(float v) {
    v += __int_as_float(__builtin_amdgcn_mov_dpp(__float_as_int(v), 0xB1, 0xF, 0xF, true)); // xor 1
    v += __int_as_float(__builtin_amdgcn_mov_dpp(__float_as_int(v), 0x4E, 0xF, 0xF, true)); // xor 2
    return v;
}
// broadcast quad-lane L to all 4 lanes of the quad
__device__ __forceinline__ float quad_bcast1(float v) {
    return __int_as_float(__builtin_amdgcn_mov_dpp(__float_as_int(v), 0x55, 0xF, 0xF, true));
}
__device__ __forceinline__ float quad_bcast2(float v) {
    return __int_as_float(__builtin_amdgcn_mov_dpp(__float_as_int(v), 0xAA, 0xF, 0xF, true));
}
__device__ __forceinline__ float quad_bcast3(float v) {
    return __int_as_float(__builtin_amdgcn_mov_dpp(__float_as_int(v), 0xFF, 0xF, 0xF, true));
}
// lane t <-> lane t^4 exchange (ds_swizzle BitMode xor=4, and=0x1F)
__device__ __forceinline__ float xor4_swap(float v) {
    return __int_as_float(__builtin_amdgcn_ds_swizzle(__float_as_int(v), 0x101F));
}

// f32 += f16x2 . f16x2  (v_dot2_f32_f16, full-rate on CDNA4: 2 MAC/lane/instr)
__device__ __forceinline__ float fdot2_(unsigned int w, unsigned int h, float acc) {
    asm("v_dot2_f32_f16 %0, %1, %2, %0" : "+v"(acc) : "v"(w), "v"(h));
    return acc;
}
// pack two f32 into f16x2 word with RNE rounding
__device__ __forceinline__ unsigned int pack_h2(float x, float y) {
    _Float16 a = (_Float16)x, b = (_Float16)y;
    unsigned short ua = __builtin_bit_cast(unsigned short, a);
    unsigned short ub = __builtin_bit_cast(unsigned short, b);
    return (unsigned int)ua | ((unsigned int)ub << 16);
}

// ---------------- GEMM: out[M,512] = A[M,KK] @ W[512,KK]^T + (b1+b2) ---------------
// R14: MFMA (v_mfma_f32_16x16x16f16), 64x64 tile, f16 LDS with permuted k-slots
// (both operands share the permutation -> contraction is permutation-invariant).
template <int KK, typename TA>
__global__ __launch_bounds__(256) void xg_gemm(
    const TA* __restrict__ A, const float* __restrict__ W,
    const float* __restrict__ b1, const float* __restrict__ b2,
    _Float16* __restrict__ out, int rowStride, int rowOff, int lgTc) {
    const int KP = KK + 8;               // padded row length in f16
    int m0 = blockIdx.x * 64, n0 = blockIdx.y * 64;
    int tid = threadIdx.x;
    __shared__ __align__(16) _Float16 As[64 * KP];
    __shared__ __align__(16) _Float16 Bs[64 * KP];
    const int SL = KK / 4;               // 4-elem slots per row
    const int NL = 64 * SL / 256;
    int Tcm = (1 << lgTc) - 1;
#pragma unroll
    for (int r = 0; r < NL; r++) {
        int f = r * 256 + tid;
        int mm = f / SL, kv = f % SL;
        int m = m0 + mm;
        int grow = (m >> lgTc) * rowStride + (m & Tcm) + rowOff;
        int slot = 32 * (kv >> 3) + 8 * (kv & 3) + 4 * ((kv >> 2) & 1);
        uint2 av;
        if constexpr (sizeof(TA) == 4) {
            float4 v = *(const float4*)&A[(size_t)grow * KK + 4 * kv];
            av.x = pack_h2(v.x, v.y); av.y = pack_h2(v.z, v.w);
        } else {
            av = *(const uint2*)&A[(size_t)grow * KK + 4 * kv];
        }
        *(uint2*)&As[mm * KP + slot] = av;
        float4 wv = *(const float4*)&W[(size_t)(n0 + mm) * KK + 4 * kv];
        uint2 bv; bv.x = pack_h2(wv.x, wv.y); bv.y = pack_h2(wv.z, wv.w);
        *(uint2*)&Bs[mm * KP + slot] = bv;
    }
    __syncthreads();

    int lane = tid & 63, wave = tid >> 6;
    int wm = (wave >> 1) * 32, wn = (wave & 1) * 32;
    int l15 = lane & 15, gg = lane >> 4;
    f32x4 acc[2][2] = {};
#pragma unroll
    for (int t = 0; t < KK / 32; t++) {
        int ko = 32 * t + 8 * gg;
        f16x8 a0 = *(const f16x8*)&As[(wm + l15) * KP + ko];
        f16x8 a1 = *(const f16x8*)&As[(wm + 16 + l15) * KP + ko];
        f16x8 b0 = *(const f16x8*)&Bs[(wn + l15) * KP + ko];
        f16x8 b1 = *(const f16x8*)&Bs[(wn + 16 + l15) * KP + ko];
        f16x4 a0l = __builtin_shufflevector(a0, a0, 0, 1, 2, 3);
        f16x4 a0h = __builtin_shufflevector(a0, a0, 4, 5, 6, 7);
        f16x4 a1l = __builtin_shufflevector(a1, a1, 0, 1, 2, 3);
        f16x4 a1h = __builtin_shufflevector(a1, a1, 4, 5, 6, 7);
        f16x4 b0l = __builtin_shufflevector(b0, b0, 0, 1, 2, 3);
        f16x4 b0h = __builtin_shufflevector(b0, b0, 4, 5, 6, 7);
        f16x4 b1l = __builtin_shufflevector(b1, b1, 0, 1, 2, 3);
        f16x4 b1h = __builtin_shufflevector(b1, b1, 4, 5, 6, 7);
        acc[0][0] = __builtin_amdgcn_mfma_f32_16x16x16f16(a0l, b0l, acc[0][0], 0, 0, 0);
        acc[0][1] = __builtin_amdgcn_mfma_f32_16x16x16f16(a0l, b1l, acc[0][1], 0, 0, 0);
        acc[1][0] = __builtin_amdgcn_mfma_f32_16x16x16f16(a1l, b0l, acc[1][0], 0, 0, 0);
        acc[1][1] = __builtin_amdgcn_mfma_f32_16x16x16f16(a1l, b1l, acc[1][1], 0, 0, 0);
        acc[0][0] = __builtin_amdgcn_mfma_f32_16x16x16f16(a0h, b0h, acc[0][0], 0, 0, 0);
        acc[0][1] = __builtin_amdgcn_mfma_f32_16x16x16f16(a0h, b1h, acc[0][1], 0, 0, 0);
        acc[1][0] = __builtin_amdgcn_mfma_f32_16x16x16f16(a1h, b0h, acc[1][0], 0, 0, 0);
        acc[1][1] = __builtin_amdgcn_mfma_f32_16x16x16f16(a1h, b1h, acc[1][1], 0, 0, 0);
    }
#pragma unroll
    for (int i = 0; i < 2; i++)
#pragma unroll
        for (int j = 0; j < 2; j++) {
            int col = n0 + wn + j * 16 + l15;
            float bb = b1[col] + b2[col];
#pragma unroll
            for (int r = 0; r < 4; r++) {
                size_t row = (size_t)m0 + wm + i * 16 + gg * 4 + r;
                out[row * 512 + col] = (_Float16)(acc[i][j][r] + bb);
            }
        }
}

// ---------------- Pipelined 2-layer LSTM recurrence --------------------------------
// R18 (batch-16 MFMA, 16 blocks): numerically exact but 2.6x SLOWER (occupancy
// 1.5%, VALUBusy 4.5% -> no latency hiding + DVFS). REVERTED to the 236-block
// structure. R19: 1024 threads (8 lanes/unit -> 4 waves/SIMD, 2x the TLP of R17's
// 2 waves/SIMD which measured 58% VALUBusy / 42% stall). Each lane: 16-wide
// k-slice (32 fdot2, 32 weight VGPRs -- fits the 64-VGPR cap of 1024-thr blocks);
// reduction = quad_sum + ds_swizzle xor-4 -> ALL 8 lanes hold all four full gate
// sums (two quads redundant; c maintained identically on kq8==0 and 4).
// Activation/bcast identical to R17 per quad. hb = plain 128 halfwords (32B-stride
// b128 reads, 2-way bank aliasing = free). R13 load discipline kept: x staged in
// unsigned int (no d16 false dep), 2-deep prefetch, f16 h1c. R16 LDS-only barrier.
#define KEEP(x) asm volatile("" : "+v"(x));
#define LOADW16(r) \
    _Pragma("unroll") \
    for (int j = 0; j < 4; j++) { \
        float4 v = *(const float4*)&Whh[(size_t)((r) * 128 + g) * 128 + 16 * kq8 + 4 * j]; \
        w##r[2 * j] = pack_h2(v.x, v.y); \
        w##r[2 * j + 1] = pack_h2(v.z, v.w); \
    }

__global__ void
__attribute__((amdgpu_flat_work_group_size(1024, 1024), amdgpu_waves_per_eu(4, 4)))
lstm2_rec(
    const _Float16* __restrict__ xg0, const _Float16* __restrict__ xg1,
    const float* __restrict__ Whh0, const float* __restrict__ Whh1,
    float* __restrict__ h0s, float* __restrict__ c0s,
    float* __restrict__ h1s, float* __restrict__ c1s,
    _Float16* __restrict__ h1c, float* __restrict__ p_out,
    int phase, int nch, int Tc) {
    int layer = blockIdx.y;
    if (layer == 0 && phase >= nch) return;
    if (layer == 1 && phase == 0) return;
    const _Float16* __restrict__ xg = layer ? xg1 : xg0;
    const float* __restrict__ Whh = layer ? Whh1 : Whh0;
    float* hs = layer ? h1s : h0s;
    float* cs = layer ? c1s : c0s;
    int t_start = (layer ? (phase - 1) : phase) * Tc;

    int b = blockIdx.x, t = threadIdx.x;
    int g = t >> 3, kq8 = t & 7, kq = kq8 & 3;
    __shared__ __align__(16) unsigned short hb[2][128];

    unsigned int w0[8], w1[8], w2[8], w3[8];
    LOADW16(0) LOADW16(1) LOADW16(2) LOADW16(3)
#pragma unroll
    for (int j = 0; j < 8; j++) { KEEP(w0[j]) KEEP(w1[j]) KEEP(w2[j]) KEEP(w3[j]) }

    const _Float16* xgb = xg + (size_t)b * Tc * 512;
    float c = 0.f;
    if (kq == 0) c = cs[b * 128 + g];      // kq8 in {0,4}: both keep identical c
    // 2-deep x prefetch, zero-extended into full 32-bit regs (no d16 false dep)
    unsigned int xr0 = *(const unsigned short*)&xgb[g + 128 * kq];
    unsigned int xr1 = *(const unsigned short*)&xgb[512 + g + 128 * kq];
    if (t < 64) {
        float2 hv = *(const float2*)&hs[b * 128 + 2 * t];
        ((unsigned int*)hb[0])[t] = pack_h2(hv.x, hv.y);
    }
    __syncthreads();

    int cur = 0;
    float h = 0.f;
    const int hbase = 16 * kq8;            // halfword offset of this lane's k-slice
#pragma unroll 1
    for (int tl = 0; tl < Tc; tl++) {
        unsigned int xr2 = 0;
        if (tl + 2 < Tc) xr2 = *(const unsigned short*)&xgb[(size_t)(tl + 2) * 512 + g + 128 * kq];
        uint4 hv0 = *(const uint4*)&hb[cur][hbase];
        uint4 hv1 = *(const uint4*)&hb[cur][hbase + 8];
        float acc0 = 0.f, acc1 = 0.f, acc2 = 0.f, acc3 = 0.f;
        acc0 = fdot2_(w0[0], hv0.x, acc0);
        acc0 = fdot2_(w0[1], hv0.y, acc0);
        acc0 = fdot2_(w0[2], hv0.z, acc0);
        acc0 = fdot2_(w0[3], hv0.w, acc0);
        acc0 = fdot2_(w0[4], hv1.x, acc0);
        acc0 = fdot2_(w0[5], hv1.y, acc0);
        acc0 = fdot2_(w0[6], hv1.z, acc0);
        acc0 = fdot2_(w0[7], hv1.w, acc0);
        acc1 = fdot2_(w1[0], hv0.x, acc1);
        acc1 = fdot2_(w1[1], hv0.y, acc1);
        acc1 = fdot2_(w1[2], hv0.z, acc1);
        acc1 = fdot2_(w1[3], hv0.w, acc1);
        acc1 = fdot2_(w1[4], hv1.x, acc1);
        acc1 = fdot2_(w1[5], hv1.y, acc1);
        acc1 = fdot2_(w1[6], hv1.z, acc1);
        acc1 = fdot2_(w1[7], hv1.w, acc1);
        acc2 = fdot2_(w2[0], hv0.x, acc2);
        acc2 = fdot2_(w2[1], hv0.y, acc2);
        acc2 = fdot2_(w2[2], hv0.z, acc2);
        acc2 = fdot2_(w2[3], hv0.w, acc2);
        acc2 = fdot2_(w2[4], hv1.x, acc2);
        acc2 = fdot2_(w2[5], hv1.y, acc2);
        acc2 = fdot2_(w2[6], hv1.z, acc2);
        acc2 = fdot2_(w2[7], hv1.w, acc2);
        acc3 = fdot2_(w3[0], hv0.x, acc3);
        acc3 = fdot2_(w3[1], hv0.y, acc3);
        acc3 = fdot2_(w3[2], hv0.z, acc3);
        acc3 = fdot2_(w3[3], hv0.w, acc3);
        acc3 = fdot2_(w3[4], hv1.x, acc3);
        acc3 = fdot2_(w3[5], hv1.y, acc3);
        acc3 = fdot2_(w3[6], hv1.z, acc3);
        acc3 = fdot2_(w3[7], hv1.w, acc3);
        // quad (k 0..63 | 64..127) partial sums, then xor-4 swap completes them
        float a0 = quad_sum(acc0);
        float a1 = quad_sum(acc1);
        float a2 = quad_sum(acc2);
        float a3 = quad_sum(acc3);
        a0 += xor4_swap(a0);
        a1 += xor4_swap(a1);
        a2 += xor4_swap(a2);
        a3 += xor4_swap(a3);
        // distributed activation: lane kq handles gate kq (0:i 1:f 2:g 3:o)
        float pre = (kq == 0) ? a0 : (kq == 1) ? a1 : (kq == 2) ? a2 : a3;
        pre += (float)__builtin_bit_cast(_Float16, (unsigned short)xr0);
        float m = (kq == 2) ? pre + pre : pre;       // tanh(x) = 2*sigmoid(2x)-1
        float s = 1.f / (1.f + __expf(-m));
        float act = (kq == 2) ? s + s - 1.f : s;
        float f_ = quad_bcast1(act);
        float g_ = quad_bcast2(act);
        float o_ = quad_bcast3(act);
        // valid only on kq==0 lanes (act there == sigmoid(i)); others carry garbage
        c = f_ * c + act * g_;
        h = o_ * tanhf_(c);
        unsigned short hw16 = __builtin_bit_cast(unsigned short, (_Float16)h);
        if (kq8 == 0) {
            hb[cur ^ 1][g] = hw16;
            if (layer == 0) {
                h1c[(size_t)(b * Tc + tl) * 128 + g] = __builtin_bit_cast(_Float16, hw16);
            } else if (t_start + tl == TT - 1) {
                p_out[b * 128 + g] = leaky(h);
            }
        }
        xr0 = xr1; xr1 = xr2;
        // LDS-only barrier (x prefetch + h1c store stay in flight)
        asm volatile("s_waitcnt lgkmcnt(0)" ::: "memory");
        __builtin_amdgcn_s_barrier();
        __builtin_amdgcn_sched_barrier(0);
        cur ^= 1;
    }
    if (kq8 == 0) { cs[b * 128 + g] = c; hs[b * 128 + g] = h; }
}

// ---------------- Head part 1: per-row i, everything up to n + precomputes ---------
__global__ __launch_bounds__(256) void head1_kernel(
    const float* __restrict__ x_message, const float* __restrict__ pseudo,
    const float* __restrict__ p_out,
    const float* __restrict__ Wum, const float* __restrict__ Wvm,
    const float* __restrict__ Wup, const float* __restrict__ Wvp,
    const float* __restrict__ Wpe, const float* __restrict__ bpe,
    const float* __restrict__ Whyb, const float* __restrict__ bhyb,
    const float* __restrict__ Wact, const float* __restrict__ bact,
    const float* __restrict__ Winact, const float* __restrict__ binact,
    const float* __restrict__ Wphin, const float* __restrict__ Won,
    const float* __restrict__ Weo,
    float* __restrict__ st_out, float* __restrict__ n_out, float* __restrict__ wnn_out,
    float* __restrict__ R_out, float* __restrict__ S_out,
    float* __restrict__ P_out, float* __restrict__ Q_out,
    float* __restrict__ A_out, float* __restrict__ B_out,
    float* __restrict__ d_out) {
    int i = blockIdx.x, tid = threadIdx.x;
    __shared__ float mc[769];
    __shared__ float pcp[128];
    __shared__ float um[128], vm[128], up[128], vp[128];
    __shared__ float hyb[256], nsh[256];
    __shared__ float red[4];
    __shared__ float sred[2][2];
    __shared__ float st_sh, hp0_sh, hp1_sh, wpol_sh, norm_sh;

    float s = 0.f;
    for (int q = tid; q < 768; q += 256) s += x_message[i * 768 + q];
    s = waveRedSum(s);
    if ((tid & 63) == 0) red[tid >> 6] = s;
    __syncthreads();
    if (tid == 0) {
        float tot = red[0] + red[1] + red[2] + red[3];
        float st = (tot == 0.f) ? 1.f : 0.f;
        st_sh = st; st_out[i] = st;
    }
    __syncthreads();
    float st = st_sh;
    for (int q = tid; q < 768; q += 256)
        mc[q] = (st == 1.f) ? pseudo[q] : x_message[i * 768 + q];
    if (tid == 0) mc[768] = st;
    if (tid < 128) pcp[tid] = p_out[i * 128 + tid];
    __syncthreads();

    if (tid < 128) {
        int d = tid;
        float a0 = 0.f;
        for (int q = 0; q < 769; q++) a0 += mc[q] * Wum[q * 128 + d];
        um[d] = leaky(a0);
        float a1 = 0.f;
        for (int q = 0; q < 128; q++) a1 += pcp[q] * Wup[q * 128 + d];
        a1 += st * Wup[128 * 128 + d];
        up[d] = leaky(a1);
    } else {
        int d = tid - 128;
        float a0 = 0.f;
        for (int q = 0; q < 769; q++) a0 += mc[q] * Wvm[q * 128 + d];
        vm[d] = leaky(a0);
        float a1 = 0.f;
        for (int q = 0; q < 128; q++) a1 += pcp[q] * Wvp[q * 128 + d];
        a1 += st * Wvp[128 * 128 + d];
        vp[d] = leaky(a1);
    }
    __syncthreads();

    float t0 = 0.f, t1 = 0.f;
    if (tid < 128) {
        int d = tid;
        float um_d = um[d], vp_d = vp[d], uv = um_d * vp_d;
        t0 = um_d * Wpe[d] + uv * Wpe[128 + d] + vp_d * Wpe[256 + d];
        t1 = um_d * Wpe[384 + d] + uv * Wpe[384 + 128 + d] + vp_d * Wpe[384 + 256 + d];
    }
    t0 = waveRedSum(t0); t1 = waveRedSum(t1);
    if (tid < 128 && (tid & 63) == 0) { sred[0][tid >> 6] = t0; sred[1][tid >> 6] = t1; }
    __syncthreads();
    if (tid == 0) {
        float z0 = sred[0][0] + sred[0][1] + bpe[0];
        float z1 = sred[1][0] + sred[1][1] + bpe[1];
        float mx = fmaxf(z0, z1);
        float e0 = __expf(z0 - mx), e1 = __expf(z1 - mx);
        float inv = 1.f / (e0 + e1);
        float h0 = e0 * inv, h1 = e1 * inv;
        d_out[236 + i * 2 + 0] = h0; d_out[236 + i * 2 + 1] = h1;
        hp0_sh = h0; hp1_sh = h1;
        float sgn = (z1 > z0) ? 1.f : ((z1 < z0) ? -1.f : 0.f);
        wpol_sh = (st == 0.f) ? sgn : 0.f;
    }
    __syncthreads();

    {
        float acc = bhyb[tid];
        const float* Wr = Whyb + tid * 384;
        for (int q = 0; q < 128; q++) {
            float upq = up[q], vmq = vm[q];
            acc += upq * Wr[q] + (upq + vmq) * Wr[128 + q] + vmq * Wr[256 + q];
        }
        hyb[tid] = leaky(acc);
    }
    __syncthreads();

    {
        float hp0 = hp0_sh, hp1 = hp1_sh;
        float aa = bact[tid];
        float ai = binact[tid];
        const float* Wr = Wact + tid * 258;
        const float* Wr2 = Winact + tid * 256;
        for (int q = 0; q < 256; q++) { float h = hyb[q]; aa += h * Wr[q]; ai += h * Wr2[q]; }
        aa += hp0 * Wr[256] + hp1 * Wr[257];
        float nv = leaky(aa * (1.f - st) + ai * st);
        nsh[tid] = nv; n_out[i * 256 + tid] = nv;
    }
    __syncthreads();

    float nv = nsh[tid];
    float ssum = waveRedSum(nv * nv);
    if ((tid & 63) == 0) red[tid >> 6] = ssum;
    __syncthreads();
    if (tid == 0) norm_sh = fmaxf(sqrtf(red[0] + red[1] + red[2] + red[3]), 1e-8f);
    __syncthreads();
    wnn_out[i * 256 + tid] = wpol_sh * nv / norm_sh;

    if (tid < 192) {
        float r = 0.f, sc = 0.f;
        for (int q = 0; q < 256; q++) {
            float nq = nsh[q];
            r += nq * Wphin[q * 192 + tid];
            sc += nq * Wphin[(256 + q) * 192 + tid];
        }
        R_out[i * 192 + tid] = r; S_out[i * 192 + tid] = sc;
    }
    {
        float pa = 0.f, qa = 0.f, aa = 0.f, ba = 0.f;
        for (int q = 0; q < 256; q++) {
            float nq = nsh[q];
            pa += nq * Won[q * 256 + tid];
            qa += nq * Won[(256 + q) * 256 + tid];
            aa += nq * Weo[(256 + q) * 256 + tid];
            ba += nq * Weo[(512 + q) * 256 + tid];
        }
        P_out[i * 256 + tid] = pa; Q_out[i * 256 + tid] = qa;
        A_out[i * 256 + tid] = aa; B_out[i * 256 + tid] = ba;
    }
}

// ---------------- l_ort via two-stage Gram ----------------------------------------
__global__ __launch_bounds__(256) void gram_kernel(
    const float* __restrict__ Wum, const float* __restrict__ Wvm,
    const float* __restrict__ Wup, const float* __restrict__ Wvp,
    float* __restrict__ G) {
    int which = blockIdx.y;
    const float* __restrict__ M = (which == 0) ? Wum : (which == 1) ? Wvm
                                 : (which == 2) ? Wup : Wvp;
    int R = (which < 2) ? 769 : 129;
    int tile = blockIdx.x;               // 16 tiles of 32x32 over the 128x128 output
    int ti = (tile >> 2) * 32, tj = (tile & 3) * 32;
    int t = threadIdx.x;
    __shared__ __align__(16) float Ls[64][32];
    __shared__ __align__(16) float Rs[64][32];
    int jj = t & 31, ib = (t >> 5) * 4;
    float acc0 = 0.f, acc1 = 0.f, acc2 = 0.f, acc3 = 0.f;
    for (int m0 = 0; m0 < R; m0 += 64) {
#pragma unroll
        for (int hh = 0; hh < 2; hh++) {
            int f = hh * 256 + t;        // 512 float4-slots = 64 rows x 8 segs
            int row = f >> 3, cseg = (f & 7) * 4;
            float4 lv = {0.f, 0.f, 0.f, 0.f}, rv = {0.f, 0.f, 0.f, 0.f};
            if (m0 + row < R) {
                lv = *(const float4*)&M[(size_t)(m0 + row) * 128 + ti + cseg];
                rv = *(const float4*)&M[(size_t)(m0 + row) * 128 + tj + cseg];
            }
            *(float4*)&Ls[row][cseg] = lv;
            *(float4*)&Rs[row][cseg] = rv;
        }
        __syncthreads();
#pragma unroll 4
        for (int m = 0; m < 64; m++) {
            float4 lv = *(const float4*)&Ls[m][ib];   // broadcast within 32-group
            float r = Rs[m][jj];                      // lane-distinct, conflict-free
            acc0 += lv.x * r; acc1 += lv.y * r; acc2 += lv.z * r; acc3 += lv.w * r;
        }
        __syncthreads();
    }
    float* Go = G + ((size_t)which << 14);
    Go[(size_t)(ti + ib + 0) * 128 + tj + jj] = acc0;
    Go[(size_t)(ti + ib + 1) * 128 + tj + jj] = acc1;
    Go[(size_t)(ti + ib + 2) * 128 + tj + jj] = acc2;
    Go[(size_t)(ti + ib + 3) * 128 + tj + jj] = acc3;
}

__global__ __launch_bounds__(256) void lort_red_kernel(
    const float* __restrict__ G, float* __restrict__ lort) {
    int which = blockIdx.x;              // 0: (Wum,Wvm)  1: (Wup,Wvp)
    const float* g1 = G + ((size_t)(2 * which) << 14);
    const float* g2 = g1 + (1 << 14);
    int t = threadIdx.x;
    __shared__ float red[4];
    float s = 0.f;
    for (int e = t; e < (1 << 14); e += 256) s += g1[e] * g2[e];
    s = waveRedSum(s);
    if ((t & 63) == 0) red[t >> 6] = s;
    __syncthreads();
    if (t == 0) lort[which] = red[0] + red[1] + red[2] + red[3];
}

// ---------------- phi(i,j) = leaky(R[j]+S[i]) . aphi  (stored column-major) --------
__global__ __launch_bounds__(128) void phi_kernel(
    const float* __restrict__ R, const float* __restrict__ S,
    const float* __restrict__ aphi, float* __restrict__ phi_cm) {
    int j = blockIdx.x, tid = threadIdx.x;
    __shared__ float rj[192], ap[192];
    for (int q = tid; q < 192; q += 128) { rj[q] = R[j * 192 + q]; ap[q] = aphi[q]; }
    __syncthreads();
    if (tid < NN) {
        const float* Si = S + tid * 192;
        float acc = 0.f;
        for (int d = 0; d < 192; d++) acc += leaky(rj[d] + Si[d]) * ap[d];
        phi_cm[j * NN + tid] = acc;
    }
}

// ---------------- double group-softmax over rows, per column ----------------------
__global__ __launch_bounds__(128) void alpha_kernel(
    const float* __restrict__ phi_cm, const float* __restrict__ stv,
    float* __restrict__ w0_cm, float* __restrict__ w1_cm) {
    int j = blockIdx.x, tid = threadIdx.x;
    __shared__ float sm[2][2], ssum[2][2];
    bool act = tid < NN;
    float sti = act ? stv[tid] : -1.f;
    float v = act ? phi_cm[j * NN + tid] : 0.f;
    float m0 = (sti == 0.f) ? v : -3.0e38f;
    float m1 = (sti == 1.f) ? v : -3.0e38f;
    float M0 = waveRedMax(m0), M1 = waveRedMax(m1);
    if ((tid & 63) == 0) { sm[tid >> 6][0] = M0; sm[tid >> 6][1] = M1; }
    __syncthreads();
    M0 = fmaxf(sm[0][0], sm[1][0]); M1 = fmaxf(sm[0][1], sm[1][1]);
    float e = 0.f;
    if (act) e = __expf(v - ((sti == 0.f) ? M0 : M1));
    float e0 = (sti == 0.f) ? e : 0.f, e1 = (sti == 1.f) ? e : 0.f;
    float S0 = waveRedSum(e0), S1 = waveRedSum(e1);
    if ((tid & 63) == 0) { ssum[tid >> 6][0] = S0; ssum[tid >> 6][1] = S1; }
    __syncthreads();
    S0 = ssum[0][0] + ssum[1][0]; S1 = ssum[0][1] + ssum[1][1];
    if (act) {
        float alpha = e / ((sti == 0.f) ? S0 : S1);
        w0_cm[j * NN + tid] = sti * alpha;
        w1_cm[j * NN + tid] = (1.f - sti) * alpha;
    }
}

// ---------------- per-row weighted sums over j ------------------------------------
__global__ __launch_bounds__(256) void qsum_kernel(
    const float* __restrict__ P, const float* __restrict__ Q, const float* __restrict__ Ab,
    const float* __restrict__ w0_cm, const float* __restrict__ w1_cm,
    float* __restrict__ qs0, float* __restrict__ qs1,
    float* __restrict__ as0, float* __restrict__ as1,
    float* __restrict__ ws0, float* __restrict__ ws1) {
    int i = blockIdx.x, d = threadIdx.x;
    float Qd = Q[i * 256 + d];
    float q0 = 0.f, q1 = 0.f, a0 = 0.f, a1 = 0.f, s0 = 0.f, s1 = 0.f;
    for (int jj = 0; jj < NN; jj++) {
        float w0 = w0_cm[jj * NN + i], w1 = w1_cm[jj * NN + i];
        float pq = leaky(P[jj * 256 + d] + Qd);
        float av = Ab[jj * 256 + d];
        q0 += w0 * pq; q1 += w1 * pq;
        a0 += w0 * av; a1 += w1 * av;
        s0 += w0; s1 += w1;
    }
    qs0[i * 256 + d] = q0; qs1[i * 256 + d] = q1;
    as0[i * 256 + d] = a0; as1[i * 256 + d] = a1;
    if (d == 0) { ws0[i] = s0; ws1[i] = s1; }
}

// ---------------- hm0/hm1, output head, y_hat -------------------------------------
__global__ __launch_bounds__(256) void hm_out_kernel(
    const float* __restrict__ qs0, const float* __restrict__ qs1,
    const float* __restrict__ as0, const float* __restrict__ as1,
    const float* __restrict__ ws0, const float* __restrict__ ws1,
    const float* __restrict__ Bb, const float* __restrict__ nbuf,
    const float* __restrict__ Weo, const float* __restrict__ Wi,
    const float* __restrict__ bi, float* __restrict__ d_out) {
    int i = blockIdx.x, d = threadIdx.x;
    __shared__ float q0sh[256], q1sh[256];
    __shared__ float r0[4], r1[4];
    q0sh[d] = qs0[i * 256 + d]; q1sh[d] = qs1[i * 256 + d];
    __syncthreads();
    float Bd = Bb[i * 256 + d];
    float h0 = as0[i * 256 + d] + ws0[i] * Bd;
    float h1 = as1[i * 256 + d] + ws1[i] * Bd;
    for (int k = 0; k < 256; k++) {
        float w = Weo[k * 256 + d];
        h0 += q0sh[k] * w; h1 += q1sh[k] * w;
    }
    h0 = leaky(h0); h1 = leaky(h1);
    float nd = nbuf[i * 256 + d];
    const float* Wii = Wi + (size_t)i * 1536;
    float l0 = nd * Wii[d * 2] + h0 * Wii[(256 + d) * 2] + h1 * Wii[(512 + d) * 2];
    float l1 = nd * Wii[d * 2 + 1] + h0 * Wii[(256 + d) * 2 + 1] + h1 * Wii[(512 + d) * 2 + 1];
    l0 = waveRedSum(l0); l1 = waveRedSum(l1);
    if ((d & 63) == 0) { r0[d >> 6] = l0; r1[d >> 6] = l1; }
    __syncthreads();
    if (d == 0) {
        float z0 = r0[0] + r0[1] + r0[2] + r0[3] + bi[i * 2 + 0];
        float z1 = r1[0] + r1[1] + r1[2] + r1[3] + bi[i * 2 + 1];
        float mx = fmaxf(z0, z1);
        float e0 = __expf(z0 - mx), e1 = __expf(z1 - mx);
        float inv = 1.f / (e0 + e1);
        d_out[i * 2 + 0] = e0 * inv;
        d_out[i * 2 + 1] = e1 * inv;
    }
}

// ---------------- l_pol + l_ort finalize ------------------------------------------
__global__ __launch_bounds__(256) void pol_kernel(
    const float* __restrict__ wnn, const float* __restrict__ lort,
    float* __restrict__ d_out) {
    int d = threadIdx.x;
    __shared__ float red[4];
    float s = 0.f;
    for (int i = 0; i < NN; i++) s += wnn[i * 256 + d];
    float p = waveRedSum(s * s);
    if ((d & 63) == 0) red[d >> 6] = p;
    __syncthreads();
    if (d == 0) {
        d_out[473] = red[0] + red[1] + red[2] + red[3];
        d_out[472] = sqrtf(lort[0]) + sqrtf(lort[1]);
    }
}

extern "C" void kernel_launch(void* const* d_in, const int* in_sizes, int n_in,
                              void* d_out_v, int out_size, void* d_ws, size_t ws_size,
                              hipStream_t stream) {
    (void)in_sizes; (void)n_in; (void)out_size;
    const float* x        = (const float*)d_in[0];
    const float* x_msg    = (const float*)d_in[1];
    const float* pseudo   = (const float*)d_in[2];
    const float* Wih0     = (const float*)d_in[3];
    const float* Whh0     = (const float*)d_in[4];
    const float* bih0     = (const float*)d_in[5];
    const float* bhh0     = (const float*)d_in[6];
    const float* Wih1     = (const float*)d_in[7];
    const float* Whh1     = (const float*)d_in[8];
    const float* bih1     = (const float*)d_in[9];
    const float* bhh1     = (const float*)d_in[10];
    const float* Wum      = (const float*)d_in[11];
    const float* Wvm      = (const float*)d_in[12];
    const float* Wup      = (const float*)d_in[13];
    const float* Wvp      = (const float*)d_in[14];
    const float* Wpe      = (const float*)d_in[15];
    const float* bpe      = (const float*)d_in[16];
    const float* Whyb     = (const float*)d_in[17];
    const float* bhyb     = (const float*)d_in[18];
    const float* Wact     = (const float*)d_in[19];
    const float* bact     = (const float*)d_in[20];
    const float* Winact   = (const float*)d_in[21];
    const float* binact   = (const float*)d_in[22];
    const float* Wphin    = (const float*)d_in[23];
    const float* aphi     = (const float*)d_in[24];
    const float* Won      = (const float*)d_in[25];
    const float* Weo      = (const float*)d_in[26];
    const float* Wi       = (const float*)d_in[27];
    const float* bi       = (const float*)d_in[28];
    float* out = (float*)d_out_v;

    char* wsb = (char*)d_ws;
    size_t off = 0;
    auto alloc = [&](size_t nfloats) {
        float* p = (float*)(wsb + off);
        off += ((nfloats * 4 + 255) / 256) * 256;
        return p;
    };
    auto allocB = [&](size_t nbytes) {
        char* p = wsb + off;
        off += ((nbytes + 255) / 256) * 256;
        return p;
    };
    float* h0s   = alloc(NN * 128);
    float* c0s   = alloc(NN * 128);
    float* h1s   = alloc(NN * 128);
    float* c1s   = alloc(NN * 128);
    float* lort  = alloc(2);
    float* stb   = alloc(NN);
    float* p_out = alloc(NN * 128);
    float* nbuf  = alloc(NN * 256);
    float* wnn   = alloc(NN * 256);
    float* Rb    = alloc(NN * 192);
    float* Sb    = alloc(NN * 192);
    float* Pb    = alloc(NN * 256);
    float* Qb    = alloc(NN * 256);
    float* Ab    = alloc(NN * 256);
    float* Bb    = alloc(NN * 256);
    float* qs0   = alloc(NN * 256);
    float* qs1   = alloc(NN * 256);
    float* as0   = alloc(NN * 256);
    float* as1   = alloc(NN * 256);
    float* ws0   = alloc(NN);
    float* ws1   = alloc(NN);
    float* phicm = alloc(NN * NN);
    float* w0cm  = alloc(NN * NN);
    float* w1cm  = alloc(NN * NN);
    float* gramB = alloc(4 * 128 * 128);

    size_t remain = (ws_size > off) ? (ws_size - off) : 0;
    // Tc capped at 256 — lstm total = (TT+Tc)*step_time, so bigger chunks only
    // enlarge the pipeline bubble; smaller ones multiply weight-reload fetch.
    int Tc = 256;
    // need xg0 + xg1 (f16, NN*Tc*512*2 B each) + h1c (f16, NN*Tc*128*2 B)
    while (Tc > 64 && (size_t)NN * Tc * (1024 + 1024 + 256) > remain) Tc >>= 1;
    _Float16* xg0 = (_Float16*)allocB((size_t)NN * Tc * 512 * 2);
    _Float16* xg1 = (_Float16*)allocB((size_t)NN * Tc * 512 * 2);
    _Float16* h1c = (_Float16*)allocB((size_t)NN * Tc * 128 * 2);
    int lgTc = __builtin_ctz(Tc);

    hipMemsetAsync(h0s, 0, (size_t)4 * NN * 128 * sizeof(float), stream); // h0s..c1s contiguous

    int nch = TT / Tc;
    dim3 gg((NN * Tc) / 64, 8);
    // prologue: xg0 for chunk 0
    xg_gemm<64, float><<<gg, 256, 0, stream>>>(x, Wih0, bih0, bhh0, xg0, TT, 0, lgTc);
    for (int p = 0; p <= nch; p++) {
        lstm2_rec<<<dim3(NN, 2), 1024, 0, stream>>>(xg0, xg1, Whh0, Whh1,
                                                    h0s, c0s, h1s, c1s,
                                                    h1c, p_out, p, nch, Tc);
        if (p < nch)
            xg_gemm<128, _Float16><<<gg, 256, 0, stream>>>(h1c, Wih1, bih1, bhh1, xg1, Tc, 0, lgTc);
        if (p + 1 < nch)
            xg_gemm<64, float><<<gg, 256, 0, stream>>>(x, Wih0, bih0, bhh0, xg0, TT, (p + 1) * Tc, lgTc);
    }
    head1_kernel<<<NN, 256, 0, stream>>>(x_msg, pseudo, p_out, Wum, Wvm, Wup, Wvp,
                                         Wpe, bpe, Whyb, bhyb, Wact, bact, Winact, binact,
                                         Wphin, Won, Weo,
                                         stb, nbuf, wnn, Rb, Sb, Pb, Qb, Ab, Bb, out);
    gram_kernel<<<dim3(16, 4), 256, 0, stream>>>(Wum, Wvm, Wup, Wvp, gramB);
    lort_red_kernel<<<2, 256, 0, stream>>>(gramB, lort);
    phi_kernel<<<NN, 128, 0, stream>>>(Rb, Sb, aphi, phicm);
    alpha_kernel<<<NN, 128, 0, stream>>>(phicm, stb, w0cm, w1cm);
    qsum_kernel<<<NN, 256, 0, stream>>>(Pb, Qb, Ab, w0cm, w1cm, qs0, qs1, as0, as1, ws0, ws1);
    hm_out_kernel<<<NN, 256, 0, stream>>>(qs0, qs1, as0, as1, ws0, ws1, Bb, nbuf, Weo, Wi, bi, out);
    pol_kernel<<<1, 256, 0, stream>>>(wnn, lort, out);
}

// Round 14
// 2088.213 us; speedup vs baseline: 2.3606x; 1.3110x over previous
//
#include <hip/hip_runtime.h>
#include <hip/hip_bf16.h>
#include <math.h>

#define NN 118
#define TT 2048
#define NF 64
#define DP 128
#define DN 256

typedef float v2f __attribute__((ext_vector_type(2)));
typedef _Float16 f16x4 __attribute__((ext_vector_type(4)));
typedef _Float16 f16x8 __attribute__((ext_vector_type(8)));
typedef float f32x4 __attribute__((ext_vector_type(4)));

__device__ __forceinline__ float leaky(float x) { return x > 0.f ? x : 0.01f * x; }

__device__ __forceinline__ float waveRedSum(float v) {
#pragma unroll
    for (int off = 32; off > 0; off >>= 1) v += __shfl_down(v, off, 64);
    return v;
}
__device__ __forceinline__ float waveRedMax(float v) {
#pragma unroll
    for (int off = 32; off > 0; off >>= 1) v = fmaxf(v, __shfl_down(v, off, 64));
    return v;
}

__device__ __forceinline__ float sigmoidf_(float x) { return 1.0f / (1.0f + __expf(-x)); }
__device__ __forceinline__ float tanhf_(float x) { return 1.0f - 2.0f / (__expf(2.0f * x) + 1.0f); }

// sum across the 4 lanes of a quad via DPP quad_perm (VALU pipe, no LDS traffic)
__device__ __forceinline__ float quad_sum(float v) {
    v += __int_as_float(__builtin_amdgcn_mov_dpp(__float_as_int(v), 0xB1, 0xF, 0xF, true)); // xor 1
    v += __int_as_float(__builtin_amdgcn_mov_dpp(__float_as_int(v), 0x4E, 0xF, 0xF, true)); // xor 2
    return v;
}
// broadcast quad-lane L to all 4 lanes of the quad
__device__ __forceinline__ float quad_bcast1(float v) {
    return __int_as_float(__builtin_amdgcn_mov_dpp(__float_as_int(v), 0x55, 0xF, 0xF, true));
}
__device__ __forceinline__ float quad_bcast2(float v) {
    return __int_as_float(__builtin_amdgcn_mov_dpp(__float_as_int(v), 0xAA, 0xF, 0xF, true));
}
__device__ __forceinline__ float quad_bcast3(float v) {
    return __int_as_float(__builtin_amdgcn_mov_dpp(__float_as_int(v), 0xFF, 0xF, 0xF, true));
}

// f32 += f16x2 . f16x2  (v_dot2_f32_f16, full-rate on CDNA4: 2 MAC/lane/instr)
__device__ __forceinline__ float fdot2_(unsigned int w, unsigned int h, float acc) {
    asm("v_dot2_f32_f16 %0, %1, %2, %0" : "+v"(acc) : "v"(w), "v"(h));
    return acc;
}
// pack two f32 into f16x2 word with RNE rounding
__device__ __forceinline__ unsigned int pack_h2(float x, float y) {
    _Float16 a = (_Float16)x, b = (_Float16)y;
    unsigned short ua = __builtin_bit_cast(unsigned short, a);
    unsigned short ub = __builtin_bit_cast(unsigned short, b);
    return (unsigned int)ua | ((unsigned int)ub << 16);
}

// ---------------- GEMM: out[M,512] = A[M,KK] @ W[512,KK]^T + (b1+b2) ---------------
// R14: MFMA (v_mfma_f32_16x16x16f16), 64x64 tile, f16 LDS with permuted k-slots
// (both operands share the permutation -> contraction is permutation-invariant).
// R20: epilogue coalescing. The direct D-layout store emitted 32 B bursts (16
// consecutive f16 per 16-lane group, rows 1 KB apart) -> half of every 64 B HBM
// write transaction wasted. Now: stage the 64x64 f16 tile into LDS (reuse As,
// stride 72; ds_write_b16 2-way aliasing = free), barrier, then 2 passes of
// 256 x b128 -- 8 consecutive threads emit one full 128 B row segment.
template <int KK, typename TA>
__global__ __launch_bounds__(256) void xg_gemm(
    const TA* __restrict__ A, const float* __restrict__ W,
    const float* __restrict__ b1, const float* __restrict__ b2,
    _Float16* __restrict__ out, int rowStride, int rowOff, int lgTc) {
    const int KP = KK + 8;               // padded row length in f16 (>= 72)
    int m0 = blockIdx.x * 64, n0 = blockIdx.y * 64;
    int tid = threadIdx.x;
    __shared__ __align__(16) _Float16 As[64 * KP];
    __shared__ __align__(16) _Float16 Bs[64 * KP];
    const int SL = KK / 4;               // 4-elem slots per row
    const int NL = 64 * SL / 256;
    int Tcm = (1 << lgTc) - 1;
#pragma unroll
    for (int r = 0; r < NL; r++) {
        int f = r * 256 + tid;
        int mm = f / SL, kv = f % SL;
        int m = m0 + mm;
        int grow = (m >> lgTc) * rowStride + (m & Tcm) + rowOff;
        int slot = 32 * (kv >> 3) + 8 * (kv & 3) + 4 * ((kv >> 2) & 1);
        uint2 av;
        if constexpr (sizeof(TA) == 4) {
            float4 v = *(const float4*)&A[(size_t)grow * KK + 4 * kv];
            av.x = pack_h2(v.x, v.y); av.y = pack_h2(v.z, v.w);
        } else {
            av = *(const uint2*)&A[(size_t)grow * KK + 4 * kv];
        }
        *(uint2*)&As[mm * KP + slot] = av;
        float4 wv = *(const float4*)&W[(size_t)(n0 + mm) * KK + 4 * kv];
        uint2 bv; bv.x = pack_h2(wv.x, wv.y); bv.y = pack_h2(wv.z, wv.w);
        *(uint2*)&Bs[mm * KP + slot] = bv;
    }
    __syncthreads();

    int lane = tid & 63, wave = tid >> 6;
    int wm = (wave >> 1) * 32, wn = (wave & 1) * 32;
    int l15 = lane & 15, gg = lane >> 4;
    f32x4 acc[2][2] = {};
#pragma unroll
    for (int t = 0; t < KK / 32; t++) {
        int ko = 32 * t + 8 * gg;
        f16x8 a0 = *(const f16x8*)&As[(wm + l15) * KP + ko];
        f16x8 a1 = *(const f16x8*)&As[(wm + 16 + l15) * KP + ko];
        f16x8 b0 = *(const f16x8*)&Bs[(wn + l15) * KP + ko];
        f16x8 b1 = *(const f16x8*)&Bs[(wn + 16 + l15) * KP + ko];
        f16x4 a0l = __builtin_shufflevector(a0, a0, 0, 1, 2, 3);
        f16x4 a0h = __builtin_shufflevector(a0, a0, 4, 5, 6, 7);
        f16x4 a1l = __builtin_shufflevector(a1, a1, 0, 1, 2, 3);
        f16x4 a1h = __builtin_shufflevector(a1, a1, 4, 5, 6, 7);
        f16x4 b0l = __builtin_shufflevector(b0, b0, 0, 1, 2, 3);
        f16x4 b0h = __builtin_shufflevector(b0, b0, 4, 5, 6, 7);
        f16x4 b1l = __builtin_shufflevector(b1, b1, 0, 1, 2, 3);
        f16x4 b1h = __builtin_shufflevector(b1, b1, 4, 5, 6, 7);
        acc[0][0] = __builtin_amdgcn_mfma_f32_16x16x16f16(a0l, b0l, acc[0][0], 0, 0, 0);
        acc[0][1] = __builtin_amdgcn_mfma_f32_16x16x16f16(a0l, b1l, acc[0][1], 0, 0, 0);
        acc[1][0] = __builtin_amdgcn_mfma_f32_16x16x16f16(a1l, b0l, acc[1][0], 0, 0, 0);
        acc[1][1] = __builtin_amdgcn_mfma_f32_16x16x16f16(a1l, b1l, acc[1][1], 0, 0, 0);
        acc[0][0] = __builtin_amdgcn_mfma_f32_16x16x16f16(a0h, b0h, acc[0][0], 0, 0, 0);
        acc[0][1] = __builtin_amdgcn_mfma_f32_16x16x16f16(a0h, b1h, acc[0][1], 0, 0, 0);
        acc[1][0] = __builtin_amdgcn_mfma_f32_16x16x16f16(a1h, b0h, acc[1][0], 0, 0, 0);
        acc[1][1] = __builtin_amdgcn_mfma_f32_16x16x16f16(a1h, b1h, acc[1][1], 0, 0, 0);
    }
    __syncthreads();                      // done reading As/Bs
#pragma unroll
    for (int i = 0; i < 2; i++)
#pragma unroll
        for (int j = 0; j < 2; j++) {
            int col = wn + j * 16 + l15;
            float bb = b1[n0 + col] + b2[n0 + col];
#pragma unroll
            for (int r = 0; r < 4; r++) {
                int row = wm + i * 16 + gg * 4 + r;
                As[row * 72 + col] = (_Float16)(acc[i][j][r] + bb);
            }
        }
    __syncthreads();
#pragma unroll
    for (int pass = 0; pass < 2; pass++) {
        int f = pass * 256 + tid;
        int row = f >> 3, seg = f & 7;   // 8 segs x 8 f16 = one 64-col row
        *(uint4*)&out[(size_t)(m0 + row) * 512 + n0 + 8 * seg] =
            *(const uint4*)&As[row * 72 + 8 * seg];
    }
}

// ---------------- Pipelined 2-layer LSTM recurrence --------------------------------
// R17/R20: reverted to the PROVEN 512-thread structure (184 us/dispatch). The
// perturbation ladder is closed: R16 LDS-only barrier (null), R18 batch-16 MFMA
// (2.6x worse, occupancy 1.5%), R19 1024-thr 4-waves/SIMD (+41%: redundant issue
// + 16-wave barrier + ds_swizzle in the chain). 1725 cyc/step is the
// latency-bound critical path of a 1-block/CU sequential recurrence.
// Kept wins: v_dot2 matvec from 64 VGPR f16x2 weight words (R9), x staged in
// unsigned int (no d16 false dep) + 2-deep prefetch (R13), f16 h via ds_write_b16
// (R12), f16 h1c (R13), LDS-only step barrier (R16).
#define KEEP(x) asm volatile("" : "+v"(x));
#define LOADW8(r) \
    _Pragma("unroll") \
    for (int j = 0; j < 4; j++) { \
        float4 t0 = *(const float4*)&Whh[(size_t)(g + 128 * (r)) * 128 + kq * 32 + 8 * j]; \
        float4 t1 = *(const float4*)&Whh[(size_t)(g + 128 * (r)) * 128 + kq * 32 + 8 * j + 4]; \
        w##r[4 * j + 0] = pack_h2(t0.x, t0.y); \
        w##r[4 * j + 1] = pack_h2(t0.z, t0.w); \
        w##r[4 * j + 2] = pack_h2(t1.x, t1.y); \
        w##r[4 * j + 3] = pack_h2(t1.z, t1.w); \
    }

__global__ void
__attribute__((amdgpu_flat_work_group_size(512, 512), amdgpu_waves_per_eu(2, 2)))
lstm2_rec(
    const _Float16* __restrict__ xg0, const _Float16* __restrict__ xg1,
    const float* __restrict__ Whh0, const float* __restrict__ Whh1,
    float* __restrict__ h0s, float* __restrict__ c0s,
    float* __restrict__ h1s, float* __restrict__ c1s,
    _Float16* __restrict__ h1c, float* __restrict__ p_out,
    int phase, int nch, int Tc) {
    int layer = blockIdx.y;
    if (layer == 0 && phase >= nch) return;
    if (layer == 1 && phase == 0) return;
    const _Float16* __restrict__ xg = layer ? xg1 : xg0;
    const float* __restrict__ Whh = layer ? Whh1 : Whh0;
    float* hs = layer ? h1s : h0s;
    float* cs = layer ? c1s : c0s;
    int t_start = (layer ? (phase - 1) : phase) * Tc;

    int b = blockIdx.x, t = threadIdx.x;
    int g = t >> 2, kq = t & 3;
    // h as f16 halfwords: 2 buffers x 4 groups x (32 h + 8 pad); group stride 80 B
    // keeps b128 reads 16B-aligned; 4 broadcast addrs per wave read (conflict-free).
    __shared__ __align__(16) unsigned short hb[2][160];

    unsigned int w0[16], w1[16], w2[16], w3[16];
    LOADW8(0) LOADW8(1) LOADW8(2) LOADW8(3)
#pragma unroll
    for (int j = 0; j < 16; j++) { KEEP(w0[j]) KEEP(w1[j]) KEEP(w2[j]) KEEP(w3[j]) }

    const _Float16* xgb = xg + (size_t)b * Tc * 512;
    float c = 0.f;
    if (kq == 0) c = cs[b * 128 + g];
    // 2-deep x prefetch, zero-extended into full 32-bit regs (no d16 false dep)
    unsigned int xr0 = *(const unsigned short*)&xgb[g + 128 * kq];
    unsigned int xr1 = *(const unsigned short*)&xgb[512 + g + 128 * kq];
    if (t < 64) {
        float2 hv = *(const float2*)&hs[b * 128 + 2 * t];
        ((unsigned int*)hb[0])[(t >> 4) * 20 + (t & 15)] = pack_h2(hv.x, hv.y);
    }
    __syncthreads();

    int cur = 0;
    float h = 0.f;
    const int hbase = kq * 40;   // halfword offset of this lane's K-quarter
#pragma unroll 1
    for (int tl = 0; tl < Tc; tl++) {
        unsigned int xr2 = 0;
        if (tl + 2 < Tc) xr2 = *(const unsigned short*)&xgb[(size_t)(tl + 2) * 512 + g + 128 * kq];
        float acc0 = 0.f, acc1 = 0.f, acc2 = 0.f, acc3 = 0.f;
#pragma unroll
        for (int k = 0; k < 4; k++) {
            uint4 hv = *(const uint4*)&hb[cur][hbase + 8 * k];
            acc0 = fdot2_(w0[4 * k + 0], hv.x, acc0);
            acc0 = fdot2_(w0[4 * k + 1], hv.y, acc0);
            acc0 = fdot2_(w0[4 * k + 2], hv.z, acc0);
            acc0 = fdot2_(w0[4 * k + 3], hv.w, acc0);
            acc1 = fdot2_(w1[4 * k + 0], hv.x, acc1);
            acc1 = fdot2_(w1[4 * k + 1], hv.y, acc1);
            acc1 = fdot2_(w1[4 * k + 2], hv.z, acc1);
            acc1 = fdot2_(w1[4 * k + 3], hv.w, acc1);
            acc2 = fdot2_(w2[4 * k + 0], hv.x, acc2);
            acc2 = fdot2_(w2[4 * k + 1], hv.y, acc2);
            acc2 = fdot2_(w2[4 * k + 2], hv.z, acc2);
            acc2 = fdot2_(w2[4 * k + 3], hv.w, acc2);
            acc3 = fdot2_(w3[4 * k + 0], hv.x, acc3);
            acc3 = fdot2_(w3[4 * k + 1], hv.y, acc3);
            acc3 = fdot2_(w3[4 * k + 2], hv.z, acc3);
            acc3 = fdot2_(w3[4 * k + 3], hv.w, acc3);
        }
        float a0 = quad_sum(acc0);
        float a1 = quad_sum(acc1);
        float a2 = quad_sum(acc2);
        float a3 = quad_sum(acc3);
        // distributed activation: lane kq handles gate kq (0:i 1:f 2:g 3:o)
        float pre = (kq == 0) ? a0 : (kq == 1) ? a1 : (kq == 2) ? a2 : a3;
        pre += (float)__builtin_bit_cast(_Float16, (unsigned short)xr0);
        float m = (kq == 2) ? pre + pre : pre;       // tanh(x) = 2*sigmoid(2x)-1
        float s = 1.f / (1.f + __expf(-m));
        float act = (kq == 2) ? s + s - 1.f : s;
        float f_ = quad_bcast1(act);
        float g_ = quad_bcast2(act);
        float o_ = quad_bcast3(act);
        // valid only on kq==0 lanes (act there == sigmoid(i)); others carry garbage
        c = f_ * c + act * g_;
        h = o_ * tanhf_(c);
        unsigned short hw16 = __builtin_bit_cast(unsigned short, (_Float16)h);
        if (kq == 0) {
            hb[cur ^ 1][(g >> 5) * 40 + (g & 31)] = hw16;
            if (layer == 0) {
                h1c[(size_t)(b * Tc + tl) * 128 + g] = __builtin_bit_cast(_Float16, hw16);
            } else if (t_start + tl == TT - 1) {
                p_out[b * 128 + g] = leaky(h);
            }
        }
        xr0 = xr1; xr1 = xr2;
        // LDS-only barrier (x prefetch + h1c store stay in flight)
        asm volatile("s_waitcnt lgkmcnt(0)" ::: "memory");
        __builtin_amdgcn_s_barrier();
        __builtin_amdgcn_sched_barrier(0);
        cur ^= 1;
    }
    if (kq == 0) { cs[b * 128 + g] = c; hs[b * 128 + g] = h; }
}

// ---------------- Head part 1: per-row i, everything up to n + precomputes ---------
__global__ __launch_bounds__(256) void head1_kernel(
    const float* __restrict__ x_message, const float* __restrict__ pseudo,
    const float* __restrict__ p_out,
    const float* __restrict__ Wum, const float* __restrict__ Wvm,
    const float* __restrict__ Wup, const float* __restrict__ Wvp,
    const float* __restrict__ Wpe, const float* __restrict__ bpe,
    const float* __restrict__ Whyb, const float* __restrict__ bhyb,
    const float* __restrict__ Wact, const float* __restrict__ bact,
    const float* __restrict__ Winact, const float* __restrict__ binact,
    const float* __restrict__ Wphin, const float* __restrict__ Won,
    const float* __restrict__ Weo,
    float* __restrict__ st_out, float* __restrict__ n_out, float* __restrict__ wnn_out,
    float* __restrict__ R_out, float* __restrict__ S_out,
    float* __restrict__ P_out, float* __restrict__ Q_out,
    float* __restrict__ A_out, float* __restrict__ B_out,
    float* __restrict__ d_out) {
    int i = blockIdx.x, tid = threadIdx.x;
    __shared__ float mc[769];
    __shared__ float pcp[128];
    __shared__ float um[128], vm[128], up[128], vp[128];
    __shared__ float hyb[256], nsh[256];
    __shared__ float red[4];
    __shared__ float sred[2][2];
    __shared__ float st_sh, hp0_sh, hp1_sh, wpol_sh, norm_sh;

    float s = 0.f;
    for (int q = tid; q < 768; q += 256) s += x_message[i * 768 + q];
    s = waveRedSum(s);
    if ((tid & 63) == 0) red[tid >> 6] = s;
    __syncthreads();
    if (tid == 0) {
        float tot = red[0] + red[1] + red[2] + red[3];
        float st = (tot == 0.f) ? 1.f : 0.f;
        st_sh = st; st_out[i] = st;
    }
    __syncthreads();
    float st = st_sh;
    for (int q = tid; q < 768; q += 256)
        mc[q] = (st == 1.f) ? pseudo[q] : x_message[i * 768 + q];
    if (tid == 0) mc[768] = st;
    if (tid < 128) pcp[tid] = p_out[i * 128 + tid];
    __syncthreads();

    if (tid < 128) {
        int d = tid;
        float a0 = 0.f;
        for (int q = 0; q < 769; q++) a0 += mc[q] * Wum[q * 128 + d];
        um[d] = leaky(a0);
        float a1 = 0.f;
        for (int q = 0; q < 128; q++) a1 += pcp[q] * Wup[q * 128 + d];
        a1 += st * Wup[128 * 128 + d];
        up[d] = leaky(a1);
    } else {
        int d = tid - 128;
        float a0 = 0.f;
        for (int q = 0; q < 769; q++) a0 += mc[q] * Wvm[q * 128 + d];
        vm[d] = leaky(a0);
        float a1 = 0.f;
        for (int q = 0; q < 128; q++) a1 += pcp[q] * Wvp[q * 128 + d];
        a1 += st * Wvp[128 * 128 + d];
        vp[d] = leaky(a1);
    }
    __syncthreads();

    float t0 = 0.f, t1 = 0.f;
    if (tid < 128) {
        int d = tid;
        float um_d = um[d], vp_d = vp[d], uv = um_d * vp_d;
        t0 = um_d * Wpe[d] + uv * Wpe[128 + d] + vp_d * Wpe[256 + d];
        t1 = um_d * Wpe[384 + d] + uv * Wpe[384 + 128 + d] + vp_d * Wpe[384 + 256 + d];
    }
    t0 = waveRedSum(t0); t1 = waveRedSum(t1);
    if (tid < 128 && (tid & 63) == 0) { sred[0][tid >> 6] = t0; sred[1][tid >> 6] = t1; }
    __syncthreads();
    if (tid == 0) {
        float z0 = sred[0][0] + sred[0][1] + bpe[0];
        float z1 = sred[1][0] + sred[1][1] + bpe[1];
        float mx = fmaxf(z0, z1);
        float e0 = __expf(z0 - mx), e1 = __expf(z1 - mx);
        float inv = 1.f / (e0 + e1);
        float h0 = e0 * inv, h1 = e1 * inv;
        d_out[236 + i * 2 + 0] = h0; d_out[236 + i * 2 + 1] = h1;
        hp0_sh = h0; hp1_sh = h1;
        float sgn = (z1 > z0) ? 1.f : ((z1 < z0) ? -1.f : 0.f);
        wpol_sh = (st == 0.f) ? sgn : 0.f;
    }
    __syncthreads();

    {
        float acc = bhyb[tid];
        const float* Wr = Whyb + tid * 384;
        for (int q = 0; q < 128; q++) {
            float upq = up[q], vmq = vm[q];
            acc += upq * Wr[q] + (upq + vmq) * Wr[128 + q] + vmq * Wr[256 + q];
        }
        hyb[tid] = leaky(acc);
    }
    __syncthreads();

    {
        float hp0 = hp0_sh, hp1 = hp1_sh;
        float aa = bact[tid];
        float ai = binact[tid];
        const float* Wr = Wact + tid * 258;
        const float* Wr2 = Winact + tid * 256;
        for (int q = 0; q < 256; q++) { float h = hyb[q]; aa += h * Wr[q]; ai += h * Wr2[q]; }
        aa += hp0 * Wr[256] + hp1 * Wr[257];
        float nv = leaky(aa * (1.f - st) + ai * st);
        nsh[tid] = nv; n_out[i * 256 + tid] = nv;
    }
    __syncthreads();

    float nv = nsh[tid];
    float ssum = waveRedSum(nv * nv);
    if ((tid & 63) == 0) red[tid >> 6] = ssum;
    __syncthreads();
    if (tid == 0) norm_sh = fmaxf(sqrtf(red[0] + red[1] + red[2] + red[3]), 1e-8f);
    __syncthreads();
    wnn_out[i * 256 + tid] = wpol_sh * nv / norm_sh;

    if (tid < 192) {
        float r = 0.f, sc = 0.f;
        for (int q = 0; q < 256; q++) {
            float nq = nsh[q];
            r += nq * Wphin[q * 192 + tid];
            sc += nq * Wphin[(256 + q) * 192 + tid];
        }
        R_out[i * 192 + tid] = r; S_out[i * 192 + tid] = sc;
    }
    {
        float pa = 0.f, qa = 0.f, aa = 0.f, ba = 0.f;
        for (int q = 0; q < 256; q++) {
            float nq = nsh[q];
            pa += nq * Won[q * 256 + tid];
            qa += nq * Won[(256 + q) * 256 + tid];
            aa += nq * Weo[(256 + q) * 256 + tid];
            ba += nq * Weo[(512 + q) * 256 + tid];
        }
        P_out[i * 256 + tid] = pa; Q_out[i * 256 + tid] = qa;
        A_out[i * 256 + tid] = aa; B_out[i * 256 + tid] = ba;
    }
}

// ---------------- l_ort via two-stage Gram ----------------------------------------
__global__ __launch_bounds__(256) void gram_kernel(
    const float* __restrict__ Wum, const float* __restrict__ Wvm,
    const float* __restrict__ Wup, const float* __restrict__ Wvp,
    float* __restrict__ G) {
    int which = blockIdx.y;
    const float* __restrict__ M = (which == 0) ? Wum : (which == 1) ? Wvm
                                 : (which == 2) ? Wup : Wvp;
    int R = (which < 2) ? 769 : 129;
    int tile = blockIdx.x;               // 16 tiles of 32x32 over the 128x128 output
    int ti = (tile >> 2) * 32, tj = (tile & 3) * 32;
    int t = threadIdx.x;
    __shared__ __align__(16) float Ls[64][32];
    __shared__ __align__(16) float Rs[64][32];
    int jj = t & 31, ib = (t >> 5) * 4;
    float acc0 = 0.f, acc1 = 0.f, acc2 = 0.f, acc3 = 0.f;
    for (int m0 = 0; m0 < R; m0 += 64) {
#pragma unroll
        for (int hh = 0; hh < 2; hh++) {
            int f = hh * 256 + t;        // 512 float4-slots = 64 rows x 8 segs
            int row = f >> 3, cseg = (f & 7) * 4;
            float4 lv = {0.f, 0.f, 0.f, 0.f}, rv = {0.f, 0.f, 0.f, 0.f};
            if (m0 + row < R) {
                lv = *(const float4*)&M[(size_t)(m0 + row) * 128 + ti + cseg];
                rv = *(const float4*)&M[(size_t)(m0 + row) * 128 + tj + cseg];
            }
            *(float4*)&Ls[row][cseg] = lv;
            *(float4*)&Rs[row][cseg] = rv;
        }
        __syncthreads();
#pragma unroll 4
        for (int m = 0; m < 64; m++) {
            float4 lv = *(const float4*)&Ls[m][ib];   // broadcast within 32-group
            float r = Rs[m][jj];                      // lane-distinct, conflict-free
            acc0 += lv.x * r; acc1 += lv.y * r; acc2 += lv.z * r; acc3 += lv.w * r;
        }
        __syncthreads();
    }
    float* Go = G + ((size_t)which << 14);
    Go[(size_t)(ti + ib + 0) * 128 + tj + jj] = acc0;
    Go[(size_t)(ti + ib + 1) * 128 + tj + jj] = acc1;
    Go[(size_t)(ti + ib + 2) * 128 + tj + jj] = acc2;
    Go[(size_t)(ti + ib + 3) * 128 + tj + jj] = acc3;
}

__global__ __launch_bounds__(256) void lort_red_kernel(
    const float* __restrict__ G, float* __restrict__ lort) {
    int which = blockIdx.x;              // 0: (Wum,Wvm)  1: (Wup,Wvp)
    const float* g1 = G + ((size_t)(2 * which) << 14);
    const float* g2 = g1 + (1 << 14);
    int t = threadIdx.x;
    __shared__ float red[4];
    float s = 0.f;
    for (int e = t; e < (1 << 14); e += 256) s += g1[e] * g2[e];
    s = waveRedSum(s);
    if ((t & 63) == 0) red[t >> 6] = s;
    __syncthreads();
    if (t == 0) lort[which] = red[0] + red[1] + red[2] + red[3];
}

// ---------------- phi(i,j) = leaky(R[j]+S[i]) . aphi  (stored column-major) --------
__global__ __launch_bounds__(128) void phi_kernel(
    const float* __restrict__ R, const float* __restrict__ S,
    const float* __restrict__ aphi, float* __restrict__ phi_cm) {
    int j = blockIdx.x, tid = threadIdx.x;
    __shared__ float rj[192], ap[192];
    for (int q = tid; q < 192; q += 128) { rj[q] = R[j * 192 + q]; ap[q] = aphi[q]; }
    __syncthreads();
    if (tid < NN) {
        const float* Si = S + tid * 192;
        float acc = 0.f;
        for (int d = 0; d < 192; d++) acc += leaky(rj[d] + Si[d]) * ap[d];
        phi_cm[j * NN + tid] = acc;
    }
}

// ---------------- double group-softmax over rows, per column ----------------------
__global__ __launch_bounds__(128) void alpha_kernel(
    const float* __restrict__ phi_cm, const float* __restrict__ stv,
    float* __restrict__ w0_cm, float* __restrict__ w1_cm) {
    int j = blockIdx.x, tid = threadIdx.x;
    __shared__ float sm[2][2], ssum[2][2];
    bool act = tid < NN;
    float sti = act ? stv[tid] : -1.f;
    float v = act ? phi_cm[j * NN + tid] : 0.f;
    float m0 = (sti == 0.f) ? v : -3.0e38f;
    float m1 = (sti == 1.f) ? v : -3.0e38f;
    float M0 = waveRedMax(m0), M1 = waveRedMax(m1);
    if ((tid & 63) == 0) { sm[tid >> 6][0] = M0; sm[tid >> 6][1] = M1; }
    __syncthreads();
    M0 = fmaxf(sm[0][0], sm[1][0]); M1 = fmaxf(sm[0][1], sm[1][1]);
    float e = 0.f;
    if (act) e = __expf(v - ((sti == 0.f) ? M0 : M1));
    float e0 = (sti == 0.f) ? e : 0.f, e1 = (sti == 1.f) ? e : 0.f;
    float S0 = waveRedSum(e0), S1 = waveRedSum(e1);
    if ((tid & 63) == 0) { ssum[tid >> 6][0] = S0; ssum[tid >> 6][1] = S1; }
    __syncthreads();
    S0 = ssum[0][0] + ssum[1][0]; S1 = ssum[0][1] + ssum[1][1];
    if (act) {
        float alpha = e / ((sti == 0.f) ? S0 : S1);
        w0_cm[j * NN + tid] = sti * alpha;
        w1_cm[j * NN + tid] = (1.f - sti) * alpha;
    }
}

// ---------------- per-row weighted sums over j ------------------------------------
__global__ __launch_bounds__(256) void qsum_kernel(
    const float* __restrict__ P, const float* __restrict__ Q, const float* __restrict__ Ab,
    const float* __restrict__ w0_cm, const float* __restrict__ w1_cm,
    float* __restrict__ qs0, float* __restrict__ qs1,
    float* __restrict__ as0, float* __restrict__ as1,
    float* __restrict__ ws0, float* __restrict__ ws1) {
    int i = blockIdx.x, d = threadIdx.x;
    float Qd = Q[i * 256 + d];
    float q0 = 0.f, q1 = 0.f, a0 = 0.f, a1 = 0.f, s0 = 0.f, s1 = 0.f;
    for (int jj = 0; jj < NN; jj++) {
        float w0 = w0_cm[jj * NN + i], w1 = w1_cm[jj * NN + i];
        float pq = leaky(P[jj * 256 + d] + Qd);
        float av = Ab[jj * 256 + d];
        q0 += w0 * pq; q1 += w1 * pq;
        a0 += w0 * av; a1 += w1 * av;
        s0 += w0; s1 += w1;
    }
    qs0[i * 256 + d] = q0; qs1[i * 256 + d] = q1;
    as0[i * 256 + d] = a0; as1[i * 256 + d] = a1;
    if (d == 0) { ws0[i] = s0; ws1[i] = s1; }
}

// ---------------- hm0/hm1, output head, y_hat -------------------------------------
__global__ __launch_bounds__(256) void hm_out_kernel(
    const float* __restrict__ qs0, const float* __restrict__ qs1,
    const float* __restrict__ as0, const float* __restrict__ as1,
    const float* __restrict__ ws0, const float* __restrict__ ws1,
    const float* __restrict__ Bb, const float* __restrict__ nbuf,
    const float* __restrict__ Weo, const float* __restrict__ Wi,
    const float* __restrict__ bi, float* __restrict__ d_out) {
    int i = blockIdx.x, d = threadIdx.x;
    __shared__ float q0sh[256], q1sh[256];
    __shared__ float r0[4], r1[4];
    q0sh[d] = qs0[i * 256 + d]; q1sh[d] = qs1[i * 256 + d];
    __syncthreads();
    float Bd = Bb[i * 256 + d];
    float h0 = as0[i * 256 + d] + ws0[i] * Bd;
    float h1 = as1[i * 256 + d] + ws1[i] * Bd;
    for (int k = 0; k < 256; k++) {
        float w = Weo[k * 256 + d];
        h0 += q0sh[k] * w; h1 += q1sh[k] * w;
    }
    h0 = leaky(h0); h1 = leaky(h1);
    float nd = nbuf[i * 256 + d];
    const float* Wii = Wi + (size_t)i * 1536;
    float l0 = nd * Wii[d * 2] + h0 * Wii[(256 + d) * 2] + h1 * Wii[(512 + d) * 2];
    float l1 = nd * Wii[d * 2 + 1] + h0 * Wii[(256 + d) * 2 + 1] + h1 * Wii[(512 + d) * 2 + 1];
    l0 = waveRedSum(l0); l1 = waveRedSum(l1);
    if ((d & 63) == 0) { r0[d >> 6] = l0; r1[d >> 6] = l1; }
    __syncthreads();
    if (d == 0) {
        float z0 = r0[0] + r0[1] + r0[2] + r0[3] + bi[i * 2 + 0];
        float z1 = r1[0] + r1[1] + r1[2] + r1[3] + bi[i * 2 + 1];
        float mx = fmaxf(z0, z1);
        float e0 = __expf(z0 - mx), e1 = __expf(z1 - mx);
        float inv = 1.f / (e0 + e1);
        d_out[i * 2 + 0] = e0 * inv;
        d_out[i * 2 + 1] = e1 * inv;
    }
}

// ---------------- l_pol + l_ort finalize ------------------------------------------
__global__ __launch_bounds__(256) void pol_kernel(
    const float* __restrict__ wnn, const float* __restrict__ lort,
    float* __restrict__ d_out) {
    int d = threadIdx.x;
    __shared__ float red[4];
    float s = 0.f;
    for (int i = 0; i < NN; i++) s += wnn[i * 256 + d];
    float p = waveRedSum(s * s);
    if ((d & 63) == 0) red[d >> 6] = p;
    __syncthreads();
    if (d == 0) {
        d_out[473] = red[0] + red[1] + red[2] + red[3];
        d_out[472] = sqrtf(lort[0]) + sqrtf(lort[1]);
    }
}

extern "C" void kernel_launch(void* const* d_in, const int* in_sizes, int n_in,
                              void* d_out_v, int out_size, void* d_ws, size_t ws_size,
                              hipStream_t stream) {
    (void)in_sizes; (void)n_in; (void)out_size;
    const float* x        = (const float*)d_in[0];
    const float* x_msg    = (const float*)d_in[1];
    const float* pseudo   = (const float*)d_in[2];
    const float* Wih0     = (const float*)d_in[3];
    const float* Whh0     = (const float*)d_in[4];
    const float* bih0     = (const float*)d_in[5];
    const float* bhh0     = (const float*)d_in[6];
    const float* Wih1     = (const float*)d_in[7];
    const float* Whh1     = (const float*)d_in[8];
    const float* bih1     = (const float*)d_in[9];
    const float* bhh1     = (const float*)d_in[10];
    const float* Wum      = (const float*)d_in[11];
    const float* Wvm      = (const float*)d_in[12];
    const float* Wup      = (const float*)d_in[13];
    const float* Wvp      = (const float*)d_in[14];
    const float* Wpe      = (const float*)d_in[15];
    const float* bpe      = (const float*)d_in[16];
    const float* Whyb     = (const float*)d_in[17];
    const float* bhyb     = (const float*)d_in[18];
    const float* Wact     = (const float*)d_in[19];
    const float* bact     = (const float*)d_in[20];
    const float* Winact   = (const float*)d_in[21];
    const float* binact   = (const float*)d_in[22];
    const float* Wphin    = (const float*)d_in[23];
    const float* aphi     = (const float*)d_in[24];
    const float* Won      = (const float*)d_in[25];
    const float* Weo      = (const float*)d_in[26];
    const float* Wi       = (const float*)d_in[27];
    const float* bi       = (const float*)d_in[28];
    float* out = (float*)d_out_v;

    char* wsb = (char*)d_ws;
    size_t off = 0;
    auto alloc = [&](size_t nfloats) {
        float* p = (float*)(wsb + off);
        off += ((nfloats * 4 + 255) / 256) * 256;
        return p;
    };
    auto allocB = [&](size_t nbytes) {
        char* p = wsb + off;
        off += ((nbytes + 255) / 256) * 256;
        return p;
    };
    float* h0s   = alloc(NN * 128);
    float* c0s   = alloc(NN * 128);
    float* h1s   = alloc(NN * 128);
    float* c1s   = alloc(NN * 128);
    float* lort  = alloc(2);
    float* stb   = alloc(NN);
    float* p_out = alloc(NN * 128);
    float* nbuf  = alloc(NN * 256);
    float* wnn   = alloc(NN * 256);
    float* Rb    = alloc(NN * 192);
    float* Sb    = alloc(NN * 192);
    float* Pb    = alloc(NN * 256);
    float* Qb    = alloc(NN * 256);
    float* Ab    = alloc(NN * 256);
    float* Bb    = alloc(NN * 256);
    float* qs0   = alloc(NN * 256);
    float* qs1   = alloc(NN * 256);
    float* as0   = alloc(NN * 256);
    float* as1   = alloc(NN * 256);
    float* ws0   = alloc(NN);
    float* ws1   = alloc(NN);
    float* phicm = alloc(NN * NN);
    float* w0cm  = alloc(NN * NN);
    float* w1cm  = alloc(NN * NN);
    float* gramB = alloc(4 * 128 * 128);

    size_t remain = (ws_size > off) ? (ws_size - off) : 0;
    // Tc capped at 256 — lstm total = (TT+Tc)*step_time, so bigger chunks only
    // enlarge the pipeline bubble; smaller ones multiply weight-reload fetch.
    int Tc = 256;
    // need xg0 + xg1 (f16, NN*Tc*512*2 B each) + h1c (f16, NN*Tc*128*2 B)
    while (Tc > 64 && (size_t)NN * Tc * (1024 + 1024 + 256) > remain) Tc >>= 1;
    _Float16* xg0 = (_Float16*)allocB((size_t)NN * Tc * 512 * 2);
    _Float16* xg1 = (_Float16*)allocB((size_t)NN * Tc * 512 * 2);
    _Float16* h1c = (_Float16*)allocB((size_t)NN * Tc * 128 * 2);
    int lgTc = __builtin_ctz(Tc);

    hipMemsetAsync(h0s, 0, (size_t)4 * NN * 128 * sizeof(float), stream); // h0s..c1s contiguous

    int nch = TT / Tc;
    dim3 gg((NN * Tc) / 64, 8);
    // prologue: xg0 for chunk 0
    xg_gemm<64, float><<<gg, 256, 0, stream>>>(x, Wih0, bih0, bhh0, xg0, TT, 0, lgTc);
    for (int p = 0; p <= nch; p++) {
        lstm2_rec<<<dim3(NN, 2), 512, 0, stream>>>(xg0, xg1, Whh0, Whh1,
                                                   h0s, c0s, h1s, c1s,
                                                   h1c, p_out, p, nch, Tc);
        if (p < nch)
            xg_gemm<128, _Float16><<<gg, 256, 0, stream>>>(h1c, Wih1, bih1, bhh1, xg1, Tc, 0, lgTc);
        if (p + 1 < nch)
            xg_gemm<64, float><<<gg, 256, 0, stream>>>(x, Wih0, bih0, bhh0, xg0, TT, (p + 1) * Tc, lgTc);
    }
    head1_kernel<<<NN, 256, 0, stream>>>(x_msg, pseudo, p_out, Wum, Wvm, Wup, Wvp,
                                         Wpe, bpe, Whyb, bhyb, Wact, bact, Winact, binact,
                                         Wphin, Won, Weo,
                                         stb, nbuf, wnn, Rb, Sb, Pb, Qb, Ab, Bb, out);
    gram_kernel<<<dim3(16, 4), 256, 0, stream>>>(Wum, Wvm, Wup, Wvp, gramB);
    lort_red_kernel<<<2, 256, 0, stream>>>(gramB, lort);
    phi_kernel<<<NN, 128, 0, stream>>>(Rb, Sb, aphi, phicm);
    alpha_kernel<<<NN, 128, 0, stream>>>(phicm, stb, w0cm, w1cm);
    qsum_kernel<<<NN, 256, 0, stream>>>(Pb, Qb, Ab, w0cm, w1cm, qs0, qs1, as0, as1, ws0, ws1);
    hm_out_kernel<<<NN, 256, 0, stream>>>(qs0, qs1, as0, as1, ws0, ws1, Bb, nbuf, Weo, Wi, bi, out);
    pol_kernel<<<1, 256, 0, stream>>>(wnn, lort, out);
}